// Round 4
// baseline (3851.353 us; speedup 1.0000x reference)
//
#include <hip/hip_runtime.h>
#include <hip/hip_bf16.h>
#include <math.h>

typedef unsigned int uint;
typedef unsigned short ushort;

// ---------------- bf16 helpers (bit-level, RNE) ----------------
__device__ __forceinline__ float bf2f(ushort u) {
    union { uint u; float f; } v; v.u = ((uint)u) << 16; return v.f;
}
__device__ __forceinline__ ushort f2bf(float f) {
    union { float f; uint u; } v; v.f = f;
    uint r = v.u + 0x7fff + ((v.u >> 16) & 1);
    return (ushort)(r >> 16);
}
__device__ __forceinline__ float4 f4add(float4 a, float4 b) {
    return make_float4(a.x + b.x, a.y + b.y, a.z + b.z, a.w + b.w);
}
__device__ __forceinline__ float4 f4max(float4 a, float4 b) {
    return make_float4(fmaxf(a.x, b.x), fmaxf(a.y, b.y), fmaxf(a.z, b.z), fmaxf(a.w, b.w));
}
__device__ __forceinline__ float4 f4lrelu(float4 v) {
    return make_float4(v.x > 0.f ? v.x : 0.2f * v.x,
                       v.y > 0.f ? v.y : 0.2f * v.y,
                       v.z > 0.f ? v.z : 0.2f * v.z,
                       v.w > 0.f ? v.w : 0.2f * v.w);
}
__device__ __forceinline__ float f4comp(float4 v, int h) {
    return h == 0 ? v.x : (h == 1 ? v.y : (h == 2 ? v.z : v.w));
}

// ---------------- sentinel for insufficient workspace ----------------
__global__ void fail_k(float* out, int n) {
    int i = blockIdx.x * blockDim.x + threadIdx.x;
    if (i < n) out[i] = -12345.0f;
}

// ---------------- CSR build ----------------
__global__ void init_deg_k(int* __restrict__ deg, int* __restrict__ cursor, int Nn) {
    int i = blockIdx.x * blockDim.x + threadIdx.x;
    if (i < Nn) { deg[i] = 1; cursor[i] = 0; }   // 1 = self-loop
}

__global__ void count_deg_k(const int* __restrict__ edst, int* __restrict__ deg, int E) {
    int i = blockIdx.x * blockDim.x + threadIdx.x;
    if (i < E) atomicAdd(&deg[edst[i]], 1);
}

__global__ void scan_part_k(const int* __restrict__ deg, int* __restrict__ incl,
                            int* __restrict__ bsum, int Nn) {
    __shared__ int sh[256];
    int t = threadIdx.x;
    int i = blockIdx.x * 256 + t;
    int v = (i < Nn) ? deg[i] : 0;
    sh[t] = v;
    __syncthreads();
    for (int d = 1; d < 256; d <<= 1) {
        int add = (t >= d) ? sh[t - d] : 0;
        __syncthreads();
        sh[t] += add;
        __syncthreads();
    }
    if (i < Nn) incl[i] = sh[t];
    if (t == 255) bsum[blockIdx.x] = sh[255];
}

__global__ void scan_block_k(int* __restrict__ bsum, int nb) {
    __shared__ int sh[256];
    int t = threadIdx.x;
    sh[t] = (t < nb) ? bsum[t] : 0;
    __syncthreads();
    for (int d = 1; d < 256; d <<= 1) {
        int add = (t >= d) ? sh[t - d] : 0;
        __syncthreads();
        sh[t] += add;
        __syncthreads();
    }
    bsum[t] = sh[t];   // inclusive scan of block sums
}

__global__ void scan_final_k(const int* __restrict__ deg, const int* __restrict__ incl,
                             const int* __restrict__ bsum, int* __restrict__ off,
                             int Nn, int total) {
    int i = blockIdx.x * blockDim.x + threadIdx.x;
    if (i < Nn) {
        int b = i >> 8;
        int base = (b > 0) ? bsum[b - 1] : 0;
        off[i] = base + incl[i] - deg[i];   // exclusive
    }
    if (i == 0) off[Nn] = total;
}

__global__ void fill_csr_k(const int* __restrict__ esrc, const int* __restrict__ edst,
                           int E, int Nn, const int* __restrict__ off,
                           int* __restrict__ cursor, int* __restrict__ csr) {
    int i = blockIdx.x * blockDim.x + threadIdx.x;
    if (i < E) {
        int d = edst[i];
        int p = atomicAdd(&cursor[d], 1);
        csr[off[d] + p] = esrc[i];
    } else if (i < E + Nn) {
        int nd = i - E;
        int p = atomicAdd(&cursor[nd], 1);
        csr[off[nd] + p] = nd;              // self-loop
    }
}

// ---------------- GEMM: C_bf16[M,N] = A[M,K] @ B_f32[K,N] ----------------
// 128x128 tile, 8x8 micro tile, BK=16, 256 threads. fp32 accumulate, RNE to bf16.
#define GEMM_BODY(LOAD_A)                                                          \
    constexpr int BM = 128, BN = 128, BK = 16;                                     \
    __shared__ float As[BK][BM + 4];                                               \
    __shared__ float Bs[BK][BN + 4];                                               \
    const int t  = threadIdx.x;                                                    \
    const int tx = t & 15, ty = t >> 4;                                            \
    const int bm = blockIdx.x * BM;                                                \
    const int bn = blockIdx.y * BN;                                                \
    float acc[8][8] = {};                                                          \
    for (int k0 = 0; k0 < K; k0 += BK) {                                           \
        _Pragma("unroll")                                                          \
        for (int u = 0; u < 2; ++u) {                                              \
            int id = t + u * 256;                                                  \
            int m  = id >> 2;                                                      \
            int k4 = (id & 3) << 2;                                                \
            float4 av = make_float4(0.f, 0.f, 0.f, 0.f);                           \
            int gm = bm + m;                                                       \
            if (gm < M) { LOAD_A }                                                 \
            As[k4 + 0][m] = av.x;                                                  \
            As[k4 + 1][m] = av.y;                                                  \
            As[k4 + 2][m] = av.z;                                                  \
            As[k4 + 3][m] = av.w;                                                  \
            int kb = id >> 5;                                                      \
            int n4 = (id & 31) << 2;                                               \
            float4 bv = *reinterpret_cast<const float4*>(                          \
                B + (size_t)(k0 + kb) * ldb + bn + n4);                            \
            *reinterpret_cast<float4*>(&Bs[kb][n4]) = bv;                          \
        }                                                                          \
        __syncthreads();                                                           \
        _Pragma("unroll")                                                          \
        for (int kk = 0; kk < BK; ++kk) {                                          \
            float a[8], b[8];                                                      \
            *(float4*)&a[0] = *(float4*)&As[kk][ty * 8];                           \
            *(float4*)&a[4] = *(float4*)&As[kk][ty * 8 + 4];                       \
            *(float4*)&b[0] = *(float4*)&Bs[kk][tx * 8];                           \
            *(float4*)&b[4] = *(float4*)&Bs[kk][tx * 8 + 4];                       \
            _Pragma("unroll")                                                      \
            for (int i = 0; i < 8; ++i)                                            \
                _Pragma("unroll")                                                  \
                for (int j = 0; j < 8; ++j)                                        \
                    acc[i][j] = fmaf(a[i], b[j], acc[i][j]);                       \
        }                                                                          \
        __syncthreads();                                                           \
    }                                                                              \
    _Pragma("unroll")                                                              \
    for (int i = 0; i < 8; ++i) {                                                  \
        int gm = bm + ty * 8 + i;                                                  \
        if (gm < M) {                                                              \
            uint4 o;                                                               \
            o.x = (uint)f2bf(acc[i][0]) | ((uint)f2bf(acc[i][1]) << 16);           \
            o.y = (uint)f2bf(acc[i][2]) | ((uint)f2bf(acc[i][3]) << 16);           \
            o.z = (uint)f2bf(acc[i][4]) | ((uint)f2bf(acc[i][5]) << 16);           \
            o.w = (uint)f2bf(acc[i][6]) | ((uint)f2bf(acc[i][7]) << 16);           \
            *reinterpret_cast<uint4*>(C + (size_t)gm * ldc + bn + tx * 8) = o;     \
        }                                                                          \
    }

__global__ __launch_bounds__(256) void gemm_f32a_k(
    const float* __restrict__ A, int lda, const float* __restrict__ B, int ldb,
    ushort* __restrict__ C, int ldc, int M, int K) {
    GEMM_BODY(av = *reinterpret_cast<const float4*>(A + (size_t)gm * lda + k0 + k4);)
}

__global__ __launch_bounds__(256) void gemm_bf16a_k(
    const ushort* __restrict__ A, int lda, const float* __restrict__ B, int ldb,
    ushort* __restrict__ C, int ldc, int M, int K) {
    GEMM_BODY(
        ushort4 u4 = *reinterpret_cast<const ushort4*>(A + (size_t)gm * lda + k0 + k4);
        av = make_float4(bf2f(u4.x), bf2f(u4.y), bf2f(u4.z), bf2f(u4.w));)
}

// ---------------- attention score dots: s[n,h] = sum_c h[n,h,c]*a[h,c] ----------------
template <int C>
__global__ void attn_scores_k(const ushort* __restrict__ h,
                              const float* __restrict__ asrc,
                              const float* __restrict__ adst,
                              float* __restrict__ ssrc, float* __restrict__ sdst) {
    constexpr int NT = C;        // threads; each handles 4 channels
    constexpr int G  = C / 4;    // threads per head
    int n = blockIdx.x, t = threadIdx.x;
    ushort4 hu = *reinterpret_cast<const ushort4*>(h + (size_t)n * 4 * C + 4 * t);
    float4 hv = make_float4(bf2f(hu.x), bf2f(hu.y), bf2f(hu.z), bf2f(hu.w));
    float4 av = *reinterpret_cast<const float4*>(asrc + 4 * t);
    float4 dv = *reinterpret_cast<const float4*>(adst + 4 * t);
    float ps = hv.x * av.x + hv.y * av.y + hv.z * av.z + hv.w * av.w;
    float pd = hv.x * dv.x + hv.y * dv.y + hv.z * dv.z + hv.w * dv.w;
    __shared__ float rs[NT], rd[NT];
    rs[t] = ps; rd[t] = pd;
    __syncthreads();
    for (int s_ = G / 2; s_ > 0; s_ >>= 1) {
        if ((t & (G - 1)) < s_) { rs[t] += rs[t + s_]; rd[t] += rd[t + s_]; }
        __syncthreads();
    }
    if ((t & (G - 1)) == 0) {
        int hh = t / G;
        ssrc[n * 4 + hh] = rs[t];
        sdst[n * 4 + hh] = rd[t];
    }
}

// ---------------- GAT softmax + aggregate (one block per dst node) ----------------
// h and out are bf16; out = cbuf [N, HC] dense.
template <int C>
__global__ void aggregate_k(const ushort* __restrict__ hmat,
                            const float* __restrict__ ssrc,
                            const float* __restrict__ sdst,
                            const int* __restrict__ off,
                            const int* __restrict__ csr,
                            const float* __restrict__ bias,
                            ushort* __restrict__ out) {
    constexpr int HC = 4 * C, NT = HC / 8;   // each thread: 8 consecutive channels
    int n = blockIdx.x, t = threadIdx.x;
    int hh = (8 * t) / C;
    int beg = off[n], end = off[n + 1];
    __shared__ float4 red[NT];
    float4 sd = *reinterpret_cast<const float4*>(sdst + n * 4);

    // pass 1: per-head max of leaky_relu(ssrc[src]+sdst[n])
    float4 m4 = make_float4(-3e38f, -3e38f, -3e38f, -3e38f);
    for (int k = beg + t; k < end; k += NT) {
        int s = csr[k];
        float4 ss = *reinterpret_cast<const float4*>(ssrc + s * 4);
        m4 = f4max(m4, f4lrelu(f4add(ss, sd)));
    }
    red[t] = m4;
    __syncthreads();
    for (int s_ = NT / 2; s_ > 0; s_ >>= 1) {
        if (t < s_) red[t] = f4max(red[t], red[t + s_]);
        __syncthreads();
    }
    m4 = red[0];
    __syncthreads();

    // pass 2: denom
    float4 d4 = make_float4(0.f, 0.f, 0.f, 0.f);
    for (int k = beg + t; k < end; k += NT) {
        int s = csr[k];
        float4 ss = *reinterpret_cast<const float4*>(ssrc + s * 4);
        float4 e = f4lrelu(f4add(ss, sd));
        d4.x += __expf(e.x - m4.x);
        d4.y += __expf(e.y - m4.y);
        d4.z += __expf(e.z - m4.z);
        d4.w += __expf(e.w - m4.w);
    }
    red[t] = d4;
    __syncthreads();
    for (int s_ = NT / 2; s_ > 0; s_ >>= 1) {
        if (t < s_) red[t] = f4add(red[t], red[t + s_]);
        __syncthreads();
    }
    d4 = red[0];

    float mh  = f4comp(m4, hh);
    float rdh = 1.0f / (f4comp(d4, hh) + 1e-16f);
    float sdh = f4comp(sd, hh);

    // pass 3: weighted aggregation over in-edges (16B bf16 gathers)
    float acc[8] = {};
    for (int k = beg; k < end; ++k) {
        int s = csr[k];
        float ev = ssrc[s * 4 + hh] + sdh;
        ev = ev > 0.f ? ev : 0.2f * ev;
        float al = __expf(ev - mh) * rdh;
        uint4 hv = *reinterpret_cast<const uint4*>(hmat + (size_t)s * HC + 8 * t);
        acc[0] = fmaf(al, bf2f((ushort)(hv.x & 0xffff)), acc[0]);
        acc[1] = fmaf(al, bf2f((ushort)(hv.x >> 16)),    acc[1]);
        acc[2] = fmaf(al, bf2f((ushort)(hv.y & 0xffff)), acc[2]);
        acc[3] = fmaf(al, bf2f((ushort)(hv.y >> 16)),    acc[3]);
        acc[4] = fmaf(al, bf2f((ushort)(hv.z & 0xffff)), acc[4]);
        acc[5] = fmaf(al, bf2f((ushort)(hv.z >> 16)),    acc[5]);
        acc[6] = fmaf(al, bf2f((ushort)(hv.w & 0xffff)), acc[6]);
        acc[7] = fmaf(al, bf2f((ushort)(hv.w >> 16)),    acc[7]);
    }
    float4 b0 = *reinterpret_cast<const float4*>(bias + 8 * t);
    float4 b1 = *reinterpret_cast<const float4*>(bias + 8 * t + 4);
    uint4 o;
    o.x = (uint)f2bf(acc[0] + b0.x) | ((uint)f2bf(acc[1] + b0.y) << 16);
    o.y = (uint)f2bf(acc[2] + b0.z) | ((uint)f2bf(acc[3] + b0.w) << 16);
    o.z = (uint)f2bf(acc[4] + b1.x) | ((uint)f2bf(acc[5] + b1.y) << 16);
    o.w = (uint)f2bf(acc[6] + b1.z) | ((uint)f2bf(acc[7] + b1.w) << 16);
    *reinterpret_cast<uint4*>(out + (size_t)n * HC + 8 * t) = o;
}

// ---------------- relu + mean pool of one layer's block into pooled[:, coloff:coloff+HC] ----------------
__global__ void pool_k(const ushort* __restrict__ c, int HC,
                       float* __restrict__ pooled, int coloff, int per) {
    int g = blockIdx.x, t = threadIdx.x;   // HC/2 threads, 2 cols each
    const uint* base = reinterpret_cast<const uint*>(c + (size_t)g * per * HC) + t;
    float a0 = 0.f, a1 = 0.f;
    for (int r = 0; r < per; ++r) {
        uint v = base[(size_t)r * (HC / 2)];
        a0 += fmaxf(bf2f((ushort)(v & 0xffff)), 0.f);
        a1 += fmaxf(bf2f((ushort)(v >> 16)), 0.f);
    }
    float inv = 1.f / (float)per;
    *reinterpret_cast<float2*>(pooled + (size_t)g * 3072 + coloff + 2 * t) =
        make_float2(a0 * inv, a1 * inv);
}

// ---------------- dense1: h1[B,1536] = relu(pooled[B,3072] @ Wd1 + bd1) ----------------
__global__ __launch_bounds__(128) void dense1_k(const float* __restrict__ pooled,
                                                const float* __restrict__ W,
                                                const float* __restrict__ bias,
                                                float* __restrict__ h1) {
    int t  = threadIdx.x;
    int j  = blockIdx.x * 128 + t;     // output col
    int g0 = blockIdx.y * 16;          // graph tile
    __shared__ float xs[16][132];
    float acc[16] = {};
    for (int r0 = 0; r0 < 3072; r0 += 128) {
#pragma unroll
        for (int u = 0; u < 4; ++u) {
            int id  = t + u * 128;     // 0..511
            int row = id >> 5;
            int c4  = (id & 31) << 2;
            *reinterpret_cast<float4*>(&xs[row][c4]) =
                *reinterpret_cast<const float4*>(pooled + (size_t)(g0 + row) * 3072 + r0 + c4);
        }
        __syncthreads();
        for (int r = 0; r < 128; r += 4) {
            float w0 = W[(size_t)(r0 + r + 0) * 1536 + j];
            float w1 = W[(size_t)(r0 + r + 1) * 1536 + j];
            float w2 = W[(size_t)(r0 + r + 2) * 1536 + j];
            float w3 = W[(size_t)(r0 + r + 3) * 1536 + j];
#pragma unroll
            for (int gg = 0; gg < 16; ++gg) {
                float4 xv = *reinterpret_cast<const float4*>(&xs[gg][r]);
                acc[gg] = fmaf(xv.x, w0, fmaf(xv.y, w1, fmaf(xv.z, w2, fmaf(xv.w, w3, acc[gg]))));
            }
        }
        __syncthreads();
    }
    float bj = bias[j];
#pragma unroll
    for (int gg = 0; gg < 16; ++gg) {
        float v = acc[gg] + bj;
        h1[(size_t)(g0 + gg) * 1536 + j] = v > 0.f ? v : 0.f;
    }
}

// ---------------- LayerNorm + final linear ----------------
__global__ __launch_bounds__(256) void ln_head_k(const float* __restrict__ h1,
                                                 const float* __restrict__ gln,
                                                 const float* __restrict__ bln,
                                                 const float* __restrict__ W2,
                                                 const float* __restrict__ b2,
                                                 float* __restrict__ out) {
    int g = blockIdx.x, t = threadIdx.x;
    const float* row = h1 + (size_t)g * 1536;
    float v[6];
    float s = 0.f;
#pragma unroll
    for (int u = 0; u < 6; ++u) { v[u] = row[t + u * 256]; s += v[u]; }
    __shared__ float red[256];
    red[t] = s;
    __syncthreads();
    for (int d = 128; d > 0; d >>= 1) { if (t < d) red[t] += red[t + d]; __syncthreads(); }
    float mean = red[0] * (1.f / 1536.f);
    __syncthreads();
    float sq = 0.f;
#pragma unroll
    for (int u = 0; u < 6; ++u) { float z = v[u] - mean; sq += z * z; }
    red[t] = sq;
    __syncthreads();
    for (int d = 128; d > 0; d >>= 1) { if (t < d) red[t] += red[t + d]; __syncthreads(); }
    float var = red[0] * (1.f / 1536.f);
    __syncthreads();
    float rstd = rsqrtf(var + 1e-5f);
    float p = 0.f;
#pragma unroll
    for (int u = 0; u < 6; ++u) {
        int j = t + u * 256;
        float xn = (v[u] - mean) * rstd * gln[j] + bln[j];
        p = fmaf(xn, W2[j], p);
    }
    red[t] = p;
    __syncthreads();
    for (int d = 128; d > 0; d >>= 1) { if (t < d) red[t] += red[t + d]; __syncthreads(); }
    if (t == 0) out[g] = red[0] + b2[0] + 0.5f;
}

// ---------------- launch ----------------
extern "C" void kernel_launch(void* const* d_in, const int* in_sizes, int n_in,
                              void* d_out, int out_size, void* d_ws, size_t ws_size,
                              hipStream_t stream) {
    const float* x    = (const float*)d_in[0];
    const int*   ei   = (const int*)d_in[1];
    const float* Wg[4]  = {(const float*)d_in[3],  (const float*)d_in[7],
                           (const float*)d_in[11], (const float*)d_in[15]};
    const float* Asr[4] = {(const float*)d_in[4],  (const float*)d_in[8],
                           (const float*)d_in[12], (const float*)d_in[16]};
    const float* Ads[4] = {(const float*)d_in[5],  (const float*)d_in[9],
                           (const float*)d_in[13], (const float*)d_in[17]};
    const float* Bg[4]  = {(const float*)d_in[6],  (const float*)d_in[10],
                           (const float*)d_in[14], (const float*)d_in[18]};
    const float* Wd1 = (const float*)d_in[19];
    const float* bd1 = (const float*)d_in[20];
    const float* gln = (const float*)d_in[21];
    const float* bln = (const float*)d_in[22];
    const float* Wd2 = (const float*)d_in[23];
    const float* bd2 = (const float*)d_in[24];

    const int Nn = in_sizes[0] / 768;   // 40000
    const int E  = in_sizes[1] / 2;     // 480000
    const int Bb = Nn / 250;            // 160

    // workspace carve (256B aligned) — total ~170 MB
    char* p = (char*)d_ws;
    auto alloc = [&](size_t bytes) -> void* {
        void* r = (void*)p;
        p += (bytes + 255) & ~(size_t)255;
        return r;
    };
    ushort* hbuf  = (ushort*)alloc((size_t)Nn * 1024 * 2);   // h (bf16), max width 1024
    ushort* cbuf  = (ushort*)alloc((size_t)Nn * 1024 * 2);   // layer output (bf16), reused in place
    float* ssrc   = (float*)alloc((size_t)Nn * 4 * 4);
    float* sdst   = (float*)alloc((size_t)Nn * 4 * 4);
    float* pooled = (float*)alloc((size_t)Bb * 3072 * 4);
    float* h1     = (float*)alloc((size_t)Bb * 1536 * 4);
    int* deg    = (int*)alloc((size_t)Nn * 4);
    int* cursor = (int*)alloc((size_t)Nn * 4);
    int* incl   = (int*)alloc((size_t)Nn * 4);
    int* bsum   = (int*)alloc(256 * 4);
    int* offs   = (int*)alloc((size_t)(Nn + 1) * 4);
    int* csr    = (int*)alloc((size_t)(E + Nn) * 4);

    size_t need = (size_t)(p - (char*)d_ws);
    if (need > ws_size) {
        // graceful fail: sentinel output instead of a device memory fault
        fail_k<<<(out_size + 255) / 256, 256, 0, stream>>>((float*)d_out, out_size);
        return;
    }

    const int* esrc = ei;
    const int* edst = ei + E;

    const int nb = (Nn + 255) / 256;    // 157
    init_deg_k<<<nb, 256, 0, stream>>>(deg, cursor, Nn);
    count_deg_k<<<(E + 255) / 256, 256, 0, stream>>>(edst, deg, E);
    scan_part_k<<<nb, 256, 0, stream>>>(deg, incl, bsum, Nn);
    scan_block_k<<<1, 256, 0, stream>>>(bsum, nb);
    scan_final_k<<<nb, 256, 0, stream>>>(deg, incl, bsum, offs, Nn, E + Nn);
    fill_csr_k<<<(E + Nn + 255) / 256, 256, 0, stream>>>(esrc, edst, E, Nn, offs, cursor, csr);

    const int Kd[4]   = {768, 512, 512, 1024};
    const int Cd[4]   = {128, 128, 256, 256};
    const int coff[4] = {0, 512, 1024, 2048};

    for (int l = 0; l < 4; ++l) {
        const int HC = 4 * Cd[l];
        dim3 gg((Nn + 127) / 128, HC / 128);
        if (l == 0)
            gemm_f32a_k<<<gg, 256, 0, stream>>>(x, 768, Wg[0], HC, hbuf, HC, Nn, 768);
        else
            gemm_bf16a_k<<<gg, 256, 0, stream>>>(cbuf, Kd[l], Wg[l], HC, hbuf, HC, Nn, Kd[l]);
        // aggregate overwrites cbuf in place: c_{l-1} is dead after the GEMM above.
        if (Cd[l] == 128) {
            attn_scores_k<128><<<Nn, 128, 0, stream>>>(hbuf, Asr[l], Ads[l], ssrc, sdst);
            aggregate_k<128><<<Nn, 64, 0, stream>>>(hbuf, ssrc, sdst, offs, csr, Bg[l], cbuf);
            pool_k<<<Bb, 256, 0, stream>>>(cbuf, 512, pooled, coff[l], 250);
        } else {
            attn_scores_k<256><<<Nn, 256, 0, stream>>>(hbuf, Asr[l], Ads[l], ssrc, sdst);
            aggregate_k<256><<<Nn, 128, 0, stream>>>(hbuf, ssrc, sdst, offs, csr, Bg[l], cbuf);
            pool_k<<<Bb, 512, 0, stream>>>(cbuf, 1024, pooled, coff[l], 250);
        }
    }

    dense1_k<<<dim3(12, Bb / 16), 128, 0, stream>>>(pooled, Wd1, bd1, h1);
    ln_head_k<<<Bb, 256, 0, stream>>>(h1, gln, bln, Wd2, bd2, (float*)d_out);
}

// Round 7
// 2027.407 us; speedup vs baseline: 1.8996x; 1.8996x over previous
//
#include <hip/hip_runtime.h>
#include <hip/hip_bf16.h>
#include <math.h>

typedef unsigned int uint;
typedef unsigned short ushort;
typedef __attribute__((ext_vector_type(8))) short bf16x8;
typedef __attribute__((ext_vector_type(4))) float f32x4;

// ---------------- bf16 helpers (bit-level, RNE) ----------------
__device__ __forceinline__ float bf2f(ushort u) {
    union { uint u; float f; } v; v.u = ((uint)u) << 16; return v.f;
}
__device__ __forceinline__ ushort f2bf(float f) {
    union { float f; uint u; } v; v.f = f;
    uint r = v.u + 0x7fff + ((v.u >> 16) & 1);
    return (ushort)(r >> 16);
}
__device__ __forceinline__ float4 f4add(float4 a, float4 b) {
    return make_float4(a.x + b.x, a.y + b.y, a.z + b.z, a.w + b.w);
}
__device__ __forceinline__ float4 f4max(float4 a, float4 b) {
    return make_float4(fmaxf(a.x, b.x), fmaxf(a.y, b.y), fmaxf(a.z, b.z), fmaxf(a.w, b.w));
}
__device__ __forceinline__ float4 f4lrelu(float4 v) {
    return make_float4(v.x > 0.f ? v.x : 0.2f * v.x,
                       v.y > 0.f ? v.y : 0.2f * v.y,
                       v.z > 0.f ? v.z : 0.2f * v.z,
                       v.w > 0.f ? v.w : 0.2f * v.w);
}
__device__ __forceinline__ float f4comp(float4 v, int h) {
    return h == 0 ? v.x : (h == 1 ? v.y : (h == 2 ? v.z : v.w));
}

__device__ __forceinline__ void gl_lds16(const void* g, void* l) {
    __builtin_amdgcn_global_load_lds(
        (const __attribute__((address_space(1))) void*)g,
        (__attribute__((address_space(3))) void*)l, 16, 0, 0);
}

// ---------------- sentinel for insufficient workspace ----------------
__global__ void fail_k(float* out, int n) {
    int i = blockIdx.x * blockDim.x + threadIdx.x;
    if (i < n) out[i] = -12345.0f;
}

// ---------------- CSR build ----------------
__global__ void init_deg_k(int* __restrict__ deg, int* __restrict__ cursor, int Nn) {
    int i = blockIdx.x * blockDim.x + threadIdx.x;
    if (i < Nn) { deg[i] = 1; cursor[i] = 0; }   // 1 = self-loop
}

__global__ void count_deg_k(const int* __restrict__ edst, int* __restrict__ deg, int E) {
    int i = blockIdx.x * blockDim.x + threadIdx.x;
    if (i < E) atomicAdd(&deg[edst[i]], 1);
}

__global__ void scan_part_k(const int* __restrict__ deg, int* __restrict__ incl,
                            int* __restrict__ bsum, int Nn) {
    __shared__ int sh[256];
    int t = threadIdx.x;
    int i = blockIdx.x * 256 + t;
    int v = (i < Nn) ? deg[i] : 0;
    sh[t] = v;
    __syncthreads();
    for (int d = 1; d < 256; d <<= 1) {
        int add = (t >= d) ? sh[t - d] : 0;
        __syncthreads();
        sh[t] += add;
        __syncthreads();
    }
    if (i < Nn) incl[i] = sh[t];
    if (t == 255) bsum[blockIdx.x] = sh[255];
}

__global__ void scan_block_k(int* __restrict__ bsum, int nb) {
    __shared__ int sh[256];
    int t = threadIdx.x;
    sh[t] = (t < nb) ? bsum[t] : 0;
    __syncthreads();
    for (int d = 1; d < 256; d <<= 1) {
        int add = (t >= d) ? sh[t - d] : 0;
        __syncthreads();
        sh[t] += add;
        __syncthreads();
    }
    bsum[t] = sh[t];   // inclusive scan of block sums
}

__global__ void scan_final_k(const int* __restrict__ deg, const int* __restrict__ incl,
                             const int* __restrict__ bsum, int* __restrict__ off,
                             int Nn, int total) {
    int i = blockIdx.x * blockDim.x + threadIdx.x;
    if (i < Nn) {
        int b = i >> 8;
        int base = (b > 0) ? bsum[b - 1] : 0;
        off[i] = base + incl[i] - deg[i];   // exclusive
    }
    if (i == 0) off[Nn] = total;
}

__global__ void fill_csr_k(const int* __restrict__ esrc, const int* __restrict__ edst,
                           int E, int Nn, const int* __restrict__ off,
                           int* __restrict__ cursor, int* __restrict__ csr) {
    int i = blockIdx.x * blockDim.x + threadIdx.x;
    if (i < E) {
        int d = edst[i];
        int p = atomicAdd(&cursor[d], 1);
        csr[off[d] + p] = esrc[i];
    } else if (i < E + Nn) {
        int nd = i - E;
        int p = atomicAdd(&cursor[nd], 1);
        csr[off[nd] + p] = nd;              // self-loop
    }
}

// ---------------- W transpose+convert: Wt[n][k] = bf16(W[k][n]) ----------------
__global__ __launch_bounds__(256) void wconv_k(const float* __restrict__ W,
                                               ushort* __restrict__ Wt, int K, int N) {
    __shared__ float tile[32][33];
    int tx = threadIdx.x, ty = threadIdx.y;      // 32 x 8
    int k0 = blockIdx.x * 32, n0 = blockIdx.y * 32;
#pragma unroll
    for (int i = 0; i < 32; i += 8)
        tile[ty + i][tx] = W[(size_t)(k0 + ty + i) * N + n0 + tx];
    __syncthreads();
#pragma unroll
    for (int i = 0; i < 32; i += 8)
        Wt[(size_t)(n0 + ty + i) * K + k0 + tx] = f2bf(tile[tx][ty + i]);
}

// ---------------- MFMA GEMM: C_bf16[Mp,N] = A[Mp,K] @ Wt^T ----------------
// 128x128 tile, BK=64, 256 threads = 4 waves (2x2), 4x4 16x16 frags/wave.
// LDS holds fragment-ordered tiles: block f = 64 lane-chunks of 16B.
// A frag layout: lane -> A[row=16*mb+(lane&15)][k=32*kb+(lane>>4)*8 ..+7]
// B frag layout: lane -> Wt[col=16*nb+(lane&15)][k=...] (B[k][col] = Wt[col][k])
template <int AF32>
__global__ __launch_bounds__(256) void gemm_mfma_k(
    const void* __restrict__ Av, const ushort* __restrict__ Bt,
    ushort* __restrict__ C, int M, int N, int K)
{
    constexpr int BM = 128, BN = 128, BK = 64;
    __shared__ __align__(16) ushort lds[(BM + BN) * BK];   // 32 KB: A then B
    ushort* Al = lds;
    ushort* Bl = lds + BM * BK;          // +8192 ushorts

    const int t = threadIdx.x;
    const int lane = t & 63;
    const int wave = t >> 6;
    const int wr = wave >> 1, wc = wave & 1;
    const int bm = blockIdx.x * BM, bn = blockIdx.y * BN;
    const int l15 = lane & 15, l16 = lane >> 4;

    f32x4 acc[4][4] = {};

    // B staging: 4 fragment-blocks per wave
    const ushort* gB[4];
    ushort* lB[4];
#pragma unroll
    for (int i = 0; i < 4; ++i) {
        int fb = wave * 4 + i, nb = fb >> 1, kb = fb & 1;
        gB[i] = Bt + (size_t)(bn + nb * 16 + l15) * K + kb * 32 + l16 * 8;
        lB[i] = Bl + fb * 512;
    }
    const ushort* gA[4] = {};
    ushort* lA[4] = {};
    const float* Af = (const float*)Av;
    int arow[4] = {}, akk[4] = {};
    if constexpr (AF32) {
#pragma unroll
        for (int i = 0; i < 4; ++i) {
            int c = t + 256 * i, fa = c >> 6, l = c & 63;
            int row = bm + (fa >> 1) * 16 + (l & 15);
            if (row >= M) row = M - 1;           // clamp: duplicate row, never stored
            arow[i] = row;
            akk[i] = (fa & 1) * 32 + (l >> 4) * 8;
        }
    } else {
        const ushort* Ab = (const ushort*)Av;
#pragma unroll
        for (int i = 0; i < 4; ++i) {
            int fa = wave * 4 + i, mb = fa >> 1, kb = fa & 1;
            gA[i] = Ab + (size_t)(bm + mb * 16 + l15) * K + kb * 32 + l16 * 8;
            lA[i] = Al + fa * 512;
        }
    }

    for (int k0 = 0; k0 < K; k0 += BK) {
        __syncthreads();                          // LDS free (prev compute done)
        if constexpr (AF32) {
#pragma unroll
            for (int i = 0; i < 4; ++i) {
                int c = t + 256 * i;
                const float* g = Af + (size_t)arow[i] * K + k0 + akk[i];
                float4 v0 = *(const float4*)g;
                float4 v1 = *(const float4*)(g + 4);
                uint4 o;
                o.x = (uint)f2bf(v0.x) | ((uint)f2bf(v0.y) << 16);
                o.y = (uint)f2bf(v0.z) | ((uint)f2bf(v0.w) << 16);
                o.z = (uint)f2bf(v1.x) | ((uint)f2bf(v1.y) << 16);
                o.w = (uint)f2bf(v1.z) | ((uint)f2bf(v1.w) << 16);
                *reinterpret_cast<uint4*>((char*)Al + (size_t)c * 16) = o;
            }
        } else {
#pragma unroll
            for (int i = 0; i < 4; ++i) { gl_lds16(gA[i], lA[i]); gA[i] += BK; }
        }
#pragma unroll
        for (int i = 0; i < 4; ++i) { gl_lds16(gB[i], lB[i]); gB[i] += BK; }
        __syncthreads();                          // stage complete (vmcnt drain)

#pragma unroll
        for (int kb = 0; kb < 2; ++kb) {
            bf16x8 a[4], b[4];
#pragma unroll
            for (int m = 0; m < 4; ++m)
                a[m] = *reinterpret_cast<const bf16x8*>(
                    Al + (((wr * 4 + m) * 2 + kb) * 64 + lane) * 8);
#pragma unroll
            for (int n = 0; n < 4; ++n)
                b[n] = *reinterpret_cast<const bf16x8*>(
                    Bl + (((wc * 4 + n) * 2 + kb) * 64 + lane) * 8);
#pragma unroll
            for (int m = 0; m < 4; ++m)
#pragma unroll
                for (int n = 0; n < 4; ++n)
                    acc[m][n] = __builtin_amdgcn_mfma_f32_16x16x32_bf16(
                        a[m], b[n], acc[m][n], 0, 0, 0);
        }
    }

    // epilogue: D reg j -> row (lane>>4)*4+j, col lane&15
#pragma unroll
    for (int m = 0; m < 4; ++m) {
        int grow0 = bm + wr * 64 + m * 16 + l16 * 4;
#pragma unroll
        for (int n = 0; n < 4; ++n) {
            int gcol = bn + wc * 64 + n * 16 + l15;
#pragma unroll
            for (int j = 0; j < 4; ++j)
                C[(size_t)(grow0 + j) * N + gcol] = f2bf(acc[m][n][j]);
        }
    }
}

// ---------------- attention score dots: s[n,h] = sum_c h[n,h,c]*a[h,c] ----------------
template <int C>
__global__ void attn_scores_k(const ushort* __restrict__ h,
                              const float* __restrict__ asrc,
                              const float* __restrict__ adst,
                              float* __restrict__ ssrc, float* __restrict__ sdst) {
    constexpr int NT = C;        // threads; each handles 4 channels
    constexpr int G  = C / 4;    // threads per head
    int n = blockIdx.x, t = threadIdx.x;
    ushort4 hu = *reinterpret_cast<const ushort4*>(h + (size_t)n * 4 * C + 4 * t);
    float4 hv = make_float4(bf2f(hu.x), bf2f(hu.y), bf2f(hu.z), bf2f(hu.w));
    float4 av = *reinterpret_cast<const float4*>(asrc + 4 * t);
    float4 dv = *reinterpret_cast<const float4*>(adst + 4 * t);
    float ps = hv.x * av.x + hv.y * av.y + hv.z * av.z + hv.w * av.w;
    float pd = hv.x * dv.x + hv.y * dv.y + hv.z * dv.z + hv.w * dv.w;
    __shared__ float rs[NT], rd[NT];
    rs[t] = ps; rd[t] = pd;
    __syncthreads();
    for (int s_ = G / 2; s_ > 0; s_ >>= 1) {
        if ((t & (G - 1)) < s_) { rs[t] += rs[t + s_]; rd[t] += rd[t + s_]; }
        __syncthreads();
    }
    if ((t & (G - 1)) == 0) {
        int hh = t / G;
        ssrc[n * 4 + hh] = rs[t];
        sdst[n * 4 + hh] = rd[t];
    }
}

// ---------------- GAT softmax + aggregate (one block per dst node) ----------------
template <int C>
__global__ void aggregate_k(const ushort* __restrict__ hmat,
                            const float* __restrict__ ssrc,
                            const float* __restrict__ sdst,
                            const int* __restrict__ off,
                            const int* __restrict__ csr,
                            const float* __restrict__ bias,
                            ushort* __restrict__ out) {
    constexpr int HC = 4 * C, NT = HC / 8;   // each thread: 8 consecutive channels
    int n = blockIdx.x, t = threadIdx.x;
    int hh = (8 * t) / C;
    int beg = off[n], end = off[n + 1];
    __shared__ float4 red[NT];
    float4 sd = *reinterpret_cast<const float4*>(sdst + n * 4);

    // pass 1: per-head max of leaky_relu(ssrc[src]+sdst[n])
    float4 m4 = make_float4(-3e38f, -3e38f, -3e38f, -3e38f);
    for (int k = beg + t; k < end; k += NT) {
        int s = csr[k];
        float4 ss = *reinterpret_cast<const float4*>(ssrc + s * 4);
        m4 = f4max(m4, f4lrelu(f4add(ss, sd)));
    }
    red[t] = m4;
    __syncthreads();
    for (int s_ = NT / 2; s_ > 0; s_ >>= 1) {
        if (t < s_) red[t] = f4max(red[t], red[t + s_]);
        __syncthreads();
    }
    m4 = red[0];
    __syncthreads();

    // pass 2: denom
    float4 d4 = make_float4(0.f, 0.f, 0.f, 0.f);
    for (int k = beg + t; k < end; k += NT) {
        int s = csr[k];
        float4 ss = *reinterpret_cast<const float4*>(ssrc + s * 4);
        float4 e = f4lrelu(f4add(ss, sd));
        d4.x += __expf(e.x - m4.x);
        d4.y += __expf(e.y - m4.y);
        d4.z += __expf(e.z - m4.z);
        d4.w += __expf(e.w - m4.w);
    }
    red[t] = d4;
    __syncthreads();
    for (int s_ = NT / 2; s_ > 0; s_ >>= 1) {
        if (t < s_) red[t] = f4add(red[t], red[t + s_]);
        __syncthreads();
    }
    d4 = red[0];

    float mh  = f4comp(m4, hh);
    float rdh = 1.0f / (f4comp(d4, hh) + 1e-16f);
    float sdh = f4comp(sd, hh);

    // pass 3: weighted aggregation over in-edges (16B bf16 gathers)
    float acc[8] = {};
    for (int k = beg; k < end; ++k) {
        int s = csr[k];
        float ev = ssrc[s * 4 + hh] + sdh;
        ev = ev > 0.f ? ev : 0.2f * ev;
        float al = __expf(ev - mh) * rdh;
        uint4 hv = *reinterpret_cast<const uint4*>(hmat + (size_t)s * HC + 8 * t);
        acc[0] = fmaf(al, bf2f((ushort)(hv.x & 0xffff)), acc[0]);
        acc[1] = fmaf(al, bf2f((ushort)(hv.x >> 16)),    acc[1]);
        acc[2] = fmaf(al, bf2f((ushort)(hv.y & 0xffff)), acc[2]);
        acc[3] = fmaf(al, bf2f((ushort)(hv.y >> 16)),    acc[3]);
        acc[4] = fmaf(al, bf2f((ushort)(hv.z & 0xffff)), acc[4]);
        acc[5] = fmaf(al, bf2f((ushort)(hv.z >> 16)),    acc[5]);
        acc[6] = fmaf(al, bf2f((ushort)(hv.w & 0xffff)), acc[6]);
        acc[7] = fmaf(al, bf2f((ushort)(hv.w >> 16)),    acc[7]);
    }
    float4 b0 = *reinterpret_cast<const float4*>(bias + 8 * t);
    float4 b1 = *reinterpret_cast<const float4*>(bias + 8 * t + 4);
    uint4 o;
    o.x = (uint)f2bf(acc[0] + b0.x) | ((uint)f2bf(acc[1] + b0.y) << 16);
    o.y = (uint)f2bf(acc[2] + b0.z) | ((uint)f2bf(acc[3] + b0.w) << 16);
    o.z = (uint)f2bf(acc[4] + b1.x) | ((uint)f2bf(acc[5] + b1.y) << 16);
    o.w = (uint)f2bf(acc[6] + b1.z) | ((uint)f2bf(acc[7] + b1.w) << 16);
    *reinterpret_cast<uint4*>(out + (size_t)n * HC + 8 * t) = o;
}

// ---------------- relu + mean pool of one layer's block into pooled[:, coloff:] ----------------
__global__ void pool_k(const ushort* __restrict__ c, int HC,
                       float* __restrict__ pooled, int coloff, int per) {
    int g = blockIdx.x, t = threadIdx.x;   // HC/2 threads, 2 cols each
    const uint* base = reinterpret_cast<const uint*>(c + (size_t)g * per * HC) + t;
    float a0 = 0.f, a1 = 0.f;
    for (int r = 0; r < per; ++r) {
        uint v = base[(size_t)r * (HC / 2)];
        a0 += fmaxf(bf2f((ushort)(v & 0xffff)), 0.f);
        a1 += fmaxf(bf2f((ushort)(v >> 16)), 0.f);
    }
    float inv = 1.f / (float)per;
    *reinterpret_cast<float2*>(pooled + (size_t)g * 3072 + coloff + 2 * t) =
        make_float2(a0 * inv, a1 * inv);
}

// ---------------- dense1: h1[B,1536] = relu(pooled[B,3072] @ Wd1 + bd1) ----------------
__global__ __launch_bounds__(128) void dense1_k(const float* __restrict__ pooled,
                                                const float* __restrict__ W,
                                                const float* __restrict__ bias,
                                                float* __restrict__ h1) {
    int t  = threadIdx.x;
    int j  = blockIdx.x * 128 + t;     // output col
    int g0 = blockIdx.y * 16;          // graph tile
    __shared__ float xs[16][132];
    float acc[16] = {};
    for (int r0 = 0; r0 < 3072; r0 += 128) {
#pragma unroll
        for (int u = 0; u < 4; ++u) {
            int id  = t + u * 128;     // 0..511
            int row = id >> 5;
            int c4  = (id & 31) << 2;
            *reinterpret_cast<float4*>(&xs[row][c4]) =
                *reinterpret_cast<const float4*>(pooled + (size_t)(g0 + row) * 3072 + r0 + c4);
        }
        __syncthreads();
        for (int r = 0; r < 128; r += 4) {
            float w0 = W[(size_t)(r0 + r + 0) * 1536 + j];
            float w1 = W[(size_t)(r0 + r + 1) * 1536 + j];
            float w2 = W[(size_t)(r0 + r + 2) * 1536 + j];
            float w3 = W[(size_t)(r0 + r + 3) * 1536 + j];
#pragma unroll
            for (int gg = 0; gg < 16; ++gg) {
                float4 xv = *reinterpret_cast<const float4*>(&xs[gg][r]);
                acc[gg] = fmaf(xv.x, w0, fmaf(xv.y, w1, fmaf(xv.z, w2, fmaf(xv.w, w3, acc[gg]))));
            }
        }
        __syncthreads();
    }
    float bj = bias[j];
#pragma unroll
    for (int gg = 0; gg < 16; ++gg) {
        float v = acc[gg] + bj;
        h1[(size_t)(g0 + gg) * 1536 + j] = v > 0.f ? v : 0.f;
    }
}

// ---------------- LayerNorm + final linear ----------------
__global__ __launch_bounds__(256) void ln_head_k(const float* __restrict__ h1,
                                                 const float* __restrict__ gln,
                                                 const float* __restrict__ bln,
                                                 const float* __restrict__ W2,
                                                 const float* __restrict__ b2,
                                                 float* __restrict__ out) {
    int g = blockIdx.x, t = threadIdx.x;
    const float* row = h1 + (size_t)g * 1536;
    float v[6];
    float s = 0.f;
#pragma unroll
    for (int u = 0; u < 6; ++u) { v[u] = row[t + u * 256]; s += v[u]; }
    __shared__ float red[256];
    red[t] = s;
    __syncthreads();
    for (int d = 128; d > 0; d >>= 1) { if (t < d) red[t] += red[t + d]; __syncthreads(); }
    float mean = red[0] * (1.f / 1536.f);
    __syncthreads();
    float sq = 0.f;
#pragma unroll
    for (int u = 0; u < 6; ++u) { float z = v[u] - mean; sq += z * z; }
    red[t] = sq;
    __syncthreads();
    for (int d = 128; d > 0; d >>= 1) { if (t < d) red[t] += red[t + d]; __syncthreads(); }
    float var = red[0] * (1.f / 1536.f);
    __syncthreads();
    float rstd = rsqrtf(var + 1e-5f);
    float p = 0.f;
#pragma unroll
    for (int u = 0; u < 6; ++u) {
        int j = t + u * 256;
        float xn = (v[u] - mean) * rstd * gln[j] + bln[j];
        p = fmaf(xn, W2[j], p);
    }
    red[t] = p;
    __syncthreads();
    for (int d = 128; d > 0; d >>= 1) { if (t < d) red[t] += red[t + d]; __syncthreads(); }
    if (t == 0) out[g] = red[0] + b2[0] + 0.5f;
}

// ---------------- launch ----------------
extern "C" void kernel_launch(void* const* d_in, const int* in_sizes, int n_in,
                              void* d_out, int out_size, void* d_ws, size_t ws_size,
                              hipStream_t stream) {
    const float* x    = (const float*)d_in[0];
    const int*   ei   = (const int*)d_in[1];
    const float* Wg[4]  = {(const float*)d_in[3],  (const float*)d_in[7],
                           (const float*)d_in[11], (const float*)d_in[15]};
    const float* Asr[4] = {(const float*)d_in[4],  (const float*)d_in[8],
                           (const float*)d_in[12], (const float*)d_in[16]};
    const float* Ads[4] = {(const float*)d_in[5],  (const float*)d_in[9],
                           (const float*)d_in[13], (const float*)d_in[17]};
    const float* Bg[4]  = {(const float*)d_in[6],  (const float*)d_in[10],
                           (const float*)d_in[14], (const float*)d_in[18]};
    const float* Wd1 = (const float*)d_in[19];
    const float* bd1 = (const float*)d_in[20];
    const float* gln = (const float*)d_in[21];
    const float* bln = (const float*)d_in[22];
    const float* Wd2 = (const float*)d_in[23];
    const float* bd2 = (const float*)d_in[24];

    const int Nn = in_sizes[0] / 768;   // 40000
    const int E  = in_sizes[1] / 2;     // 480000
    const int Bb = Nn / 250;            // 160
    const int Np = ((Nn + 127) / 128) * 128;   // 40064, padded for MFMA tiles

    const int Kd[4]   = {768, 512, 512, 1024};
    const int Cd[4]   = {128, 128, 256, 256};
    const int coff[4] = {0, 512, 1024, 2048};

    // workspace carve (256B aligned) — total ~167 MB
    char* p = (char*)d_ws;
    auto alloc = [&](size_t bytes) -> void* {
        void* r = (void*)p;
        p += (bytes + 255) & ~(size_t)255;
        return r;
    };
    ushort* hbuf  = (ushort*)alloc((size_t)Np * 1024 * 2);   // h (bf16), padded rows
    ushort* cbuf  = (ushort*)alloc((size_t)Np * 1024 * 2);   // layer output (bf16)
    ushort* wt[4];
    for (int l = 0; l < 4; ++l)
        wt[l] = (ushort*)alloc((size_t)(4 * Cd[l]) * Kd[l] * 2);  // Wt[N][K] bf16
    float* ssrc   = (float*)alloc((size_t)Nn * 4 * 4);
    float* sdst   = (float*)alloc((size_t)Nn * 4 * 4);
    float* pooled = (float*)alloc((size_t)Bb * 3072 * 4);
    float* h1     = (float*)alloc((size_t)Bb * 1536 * 4);
    int* deg    = (int*)alloc((size_t)Nn * 4);
    int* cursor = (int*)alloc((size_t)Nn * 4);
    int* incl   = (int*)alloc((size_t)Nn * 4);
    int* bsum   = (int*)alloc(256 * 4);
    int* offs   = (int*)alloc((size_t)(Nn + 1) * 4);
    int* csr    = (int*)alloc((size_t)(E + Nn) * 4);

    size_t need = (size_t)(p - (char*)d_ws);
    if (need > ws_size) {
        fail_k<<<(out_size + 255) / 256, 256, 0, stream>>>((float*)d_out, out_size);
        return;
    }

    // weight transpose+convert (independent of CSR chain)
    for (int l = 0; l < 4; ++l) {
        int N = 4 * Cd[l], K = Kd[l];
        wconv_k<<<dim3(K / 32, N / 32), dim3(32, 8), 0, stream>>>(Wg[l], wt[l], K, N);
    }

    const int* esrc = ei;
    const int* edst = ei + E;
    const int nb = (Nn + 255) / 256;    // 157
    init_deg_k<<<nb, 256, 0, stream>>>(deg, cursor, Nn);
    count_deg_k<<<(E + 255) / 256, 256, 0, stream>>>(edst, deg, E);
    scan_part_k<<<nb, 256, 0, stream>>>(deg, incl, bsum, Nn);
    scan_block_k<<<1, 256, 0, stream>>>(bsum, nb);
    scan_final_k<<<nb, 256, 0, stream>>>(deg, incl, bsum, offs, Nn, E + Nn);
    fill_csr_k<<<(E + Nn + 255) / 256, 256, 0, stream>>>(esrc, edst, E, Nn, offs, cursor, csr);

    for (int l = 0; l < 4; ++l) {
        const int HC = 4 * Cd[l];
        dim3 gg(Np / 128, HC / 128);
        if (l == 0)
            gemm_mfma_k<1><<<gg, 256, 0, stream>>>(x, wt[0], hbuf, Nn, HC, Kd[0]);
        else
            gemm_mfma_k<0><<<gg, 256, 0, stream>>>(cbuf, wt[l], hbuf, Nn, HC, Kd[l]);
        // aggregate overwrites cbuf in place: c_{l-1} is dead after the GEMM above.
        if (Cd[l] == 128) {
            attn_scores_k<128><<<Nn, 128, 0, stream>>>(hbuf, Asr[l], Ads[l], ssrc, sdst);
            aggregate_k<128><<<Nn, 64, 0, stream>>>(hbuf, ssrc, sdst, offs, csr, Bg[l], cbuf);
            pool_k<<<Bb, 256, 0, stream>>>(cbuf, 512, pooled, coff[l], 250);
        } else {
            attn_scores_k<256><<<Nn, 256, 0, stream>>>(hbuf, Asr[l], Ads[l], ssrc, sdst);
            aggregate_k<256><<<Nn, 128, 0, stream>>>(hbuf, ssrc, sdst, offs, csr, Bg[l], cbuf);
            pool_k<<<Bb, 512, 0, stream>>>(cbuf, 1024, pooled, coff[l], 250);
        }
    }

    dense1_k<<<dim3(12, Bb / 16), 128, 0, stream>>>(pooled, Wd1, bd1, h1);
    ln_head_k<<<Bb, 256, 0, stream>>>(h1, gln, bln, Wd2, bd2, (float*)d_out);
}

// Round 11
// 1632.281 us; speedup vs baseline: 2.3595x; 1.2421x over previous
//
#include <hip/hip_runtime.h>
#include <hip/hip_bf16.h>
#include <math.h>

typedef unsigned int uint;
typedef unsigned short ushort;
typedef __attribute__((ext_vector_type(8))) short bf16x8;
typedef __attribute__((ext_vector_type(4))) float f32x4;

// ---------------- bf16 helpers (bit-level, RNE) ----------------
__device__ __forceinline__ float bf2f(ushort u) {
    union { uint u; float f; } v; v.u = ((uint)u) << 16; return v.f;
}
__device__ __forceinline__ ushort f2bf(float f) {
    union { float f; uint u; } v; v.f = f;
    uint r = v.u + 0x7fff + ((v.u >> 16) & 1);
    return (ushort)(r >> 16);
}
__device__ __forceinline__ float4 f4add(float4 a, float4 b) {
    return make_float4(a.x + b.x, a.y + b.y, a.z + b.z, a.w + b.w);
}
__device__ __forceinline__ float4 f4max(float4 a, float4 b) {
    return make_float4(fmaxf(a.x, b.x), fmaxf(a.y, b.y), fmaxf(a.z, b.z), fmaxf(a.w, b.w));
}
__device__ __forceinline__ float4 f4lrelu(float4 v) {
    return make_float4(v.x > 0.f ? v.x : 0.2f * v.x,
                       v.y > 0.f ? v.y : 0.2f * v.y,
                       v.z > 0.f ? v.z : 0.2f * v.z,
                       v.w > 0.f ? v.w : 0.2f * v.w);
}
__device__ __forceinline__ float f4comp(float4 v, int h) {
    return h == 0 ? v.x : (h == 1 ? v.y : (h == 2 ? v.z : v.w));
}

__device__ __forceinline__ void gl_lds16(const void* g, void* l) {
    __builtin_amdgcn_global_load_lds(
        (const __attribute__((address_space(1))) void*)g,
        (__attribute__((address_space(3))) void*)l, 16, 0, 0);
}

// ---------------- sentinel for insufficient workspace ----------------
__global__ void fail_k(float* out, int n) {
    int i = blockIdx.x * blockDim.x + threadIdx.x;
    if (i < n) out[i] = -12345.0f;
}

// ---------------- CSR build ----------------
__global__ void init_deg_k(int* __restrict__ deg, int* __restrict__ cursor, int Nn) {
    int i = blockIdx.x * blockDim.x + threadIdx.x;
    if (i < Nn) { deg[i] = 1; cursor[i] = 0; }   // 1 = self-loop
}

__global__ void count_deg_k(const int* __restrict__ edst, int* __restrict__ deg, int E) {
    int i = blockIdx.x * blockDim.x + threadIdx.x;
    if (i < E) atomicAdd(&deg[edst[i]], 1);
}

__global__ void scan_part_k(const int* __restrict__ deg, int* __restrict__ incl,
                            int* __restrict__ bsum, int Nn) {
    __shared__ int sh[256];
    int t = threadIdx.x;
    int i = blockIdx.x * 256 + t;
    int v = (i < Nn) ? deg[i] : 0;
    sh[t] = v;
    __syncthreads();
    for (int d = 1; d < 256; d <<= 1) {
        int add = (t >= d) ? sh[t - d] : 0;
        __syncthreads();
        sh[t] += add;
        __syncthreads();
    }
    if (i < Nn) incl[i] = sh[t];
    if (t == 255) bsum[blockIdx.x] = sh[255];
}

__global__ void scan_block_k(int* __restrict__ bsum, int nb) {
    __shared__ int sh[256];
    int t = threadIdx.x;
    sh[t] = (t < nb) ? bsum[t] : 0;
    __syncthreads();
    for (int d = 1; d < 256; d <<= 1) {
        int add = (t >= d) ? sh[t - d] : 0;
        __syncthreads();
        sh[t] += add;
        __syncthreads();
    }
    bsum[t] = sh[t];   // inclusive scan of block sums
}

__global__ void scan_final_k(const int* __restrict__ deg, const int* __restrict__ incl,
                             const int* __restrict__ bsum, int* __restrict__ off,
                             int Nn, int total) {
    int i = blockIdx.x * blockDim.x + threadIdx.x;
    if (i < Nn) {
        int b = i >> 8;
        int base = (b > 0) ? bsum[b - 1] : 0;
        off[i] = base + incl[i] - deg[i];   // exclusive
    }
    if (i == 0) off[Nn] = total;
}

__global__ void fill_csr_k(const int* __restrict__ esrc, const int* __restrict__ edst,
                           int E, int Nn, const int* __restrict__ off,
                           int* __restrict__ cursor, int* __restrict__ csr) {
    int i = blockIdx.x * blockDim.x + threadIdx.x;
    if (i < E) {
        int d = edst[i];
        int p = atomicAdd(&cursor[d], 1);
        csr[off[d] + p] = esrc[i];
    } else if (i < E + Nn) {
        int nd = i - E;
        int p = atomicAdd(&cursor[nd], 1);
        csr[off[nd] + p] = nd;              // self-loop
    }
}

// ---------------- W transpose+convert: Wt[n][k] = bf16(W[k][n]) ----------------
__global__ __launch_bounds__(256) void wconv_k(const float* __restrict__ W,
                                               ushort* __restrict__ Wt, int K, int N) {
    __shared__ float tile[32][33];
    int tx = threadIdx.x, ty = threadIdx.y;      // 32 x 8
    int k0 = blockIdx.x * 32, n0 = blockIdx.y * 32;
#pragma unroll
    for (int i = 0; i < 32; i += 8)
        tile[ty + i][tx] = W[(size_t)(k0 + ty + i) * N + n0 + tx];
    __syncthreads();
#pragma unroll
    for (int i = 0; i < 32; i += 8)
        Wt[(size_t)(n0 + ty + i) * K + k0 + tx] = f2bf(tile[tx][ty + i]);
}

// ---------------- MFMA GEMM: C_bf16[Mp,N] = A[Mp,K] @ Wt^T ----------------
// 128x128 tile, BK=64, 256 threads = 4 waves (2x2), 4x4 16x16 frags/wave.
template <int AF32>
__global__ __launch_bounds__(256) void gemm_mfma_k(
    const void* __restrict__ Av, const ushort* __restrict__ Bt,
    ushort* __restrict__ C, int M, int N, int K)
{
    constexpr int BM = 128, BN = 128, BK = 64;
    __shared__ __align__(16) ushort lds[(BM + BN) * BK];   // 32 KB: A then B
    ushort* Al = lds;
    ushort* Bl = lds + BM * BK;          // +8192 ushorts

    const int t = threadIdx.x;
    const int lane = t & 63;
    const int wave = t >> 6;
    const int wr = wave >> 1, wc = wave & 1;
    const int bm = blockIdx.x * BM, bn = blockIdx.y * BN;
    const int l15 = lane & 15, l16 = lane >> 4;

    f32x4 acc[4][4] = {};

    // B staging: 4 fragment-blocks per wave
    const ushort* gB[4];
    ushort* lB[4];
#pragma unroll
    for (int i = 0; i < 4; ++i) {
        int fb = wave * 4 + i, nb = fb >> 1, kb = fb & 1;
        gB[i] = Bt + (size_t)(bn + nb * 16 + l15) * K + kb * 32 + l16 * 8;
        lB[i] = Bl + fb * 512;
    }
    const ushort* gA[4] = {};
    ushort* lA[4] = {};
    const float* Af = (const float*)Av;
    int arow[4] = {}, akk[4] = {};
    if constexpr (AF32) {
#pragma unroll
        for (int i = 0; i < 4; ++i) {
            int c = t + 256 * i, fa = c >> 6, l = c & 63;
            int row = bm + (fa >> 1) * 16 + (l & 15);
            if (row >= M) row = M - 1;           // clamp: duplicate row, never stored
            arow[i] = row;
            akk[i] = (fa & 1) * 32 + (l >> 4) * 8;
        }
    } else {
        const ushort* Ab = (const ushort*)Av;
#pragma unroll
        for (int i = 0; i < 4; ++i) {
            int fa = wave * 4 + i, mb = fa >> 1, kb = fa & 1;
            gA[i] = Ab + (size_t)(bm + mb * 16 + l15) * K + kb * 32 + l16 * 8;
            lA[i] = Al + fa * 512;
        }
    }

    for (int k0 = 0; k0 < K; k0 += BK) {
        __syncthreads();                          // LDS free (prev compute done)
        if constexpr (AF32) {
#pragma unroll
            for (int i = 0; i < 4; ++i) {
                int c = t + 256 * i;
                const float* g = Af + (size_t)arow[i] * K + k0 + akk[i];
                float4 v0 = *(const float4*)g;
                float4 v1 = *(const float4*)(g + 4);
                uint4 o;
                o.x = (uint)f2bf(v0.x) | ((uint)f2bf(v0.y) << 16);
                o.y = (uint)f2bf(v0.z) | ((uint)f2bf(v0.w) << 16);
                o.z = (uint)f2bf(v1.x) | ((uint)f2bf(v1.y) << 16);
                o.w = (uint)f2bf(v1.z) | ((uint)f2bf(v1.w) << 16);
                *reinterpret_cast<uint4*>((char*)Al + (size_t)c * 16) = o;
            }
        } else {
#pragma unroll
            for (int i = 0; i < 4; ++i) { gl_lds16(gA[i], lA[i]); gA[i] += BK; }
        }
#pragma unroll
        for (int i = 0; i < 4; ++i) { gl_lds16(gB[i], lB[i]); gB[i] += BK; }
        __syncthreads();                          // stage complete (vmcnt drain)

#pragma unroll
        for (int kb = 0; kb < 2; ++kb) {
            bf16x8 a[4], b[4];
#pragma unroll
            for (int m = 0; m < 4; ++m)
                a[m] = *reinterpret_cast<const bf16x8*>(
                    Al + (((wr * 4 + m) * 2 + kb) * 64 + lane) * 8);
#pragma unroll
            for (int n = 0; n < 4; ++n)
                b[n] = *reinterpret_cast<const bf16x8*>(
                    Bl + (((wc * 4 + n) * 2 + kb) * 64 + lane) * 8);
#pragma unroll
            for (int m = 0; m < 4; ++m)
#pragma unroll
                for (int n = 0; n < 4; ++n)
                    acc[m][n] = __builtin_amdgcn_mfma_f32_16x16x32_bf16(
                        a[m], b[n], acc[m][n], 0, 0, 0);
        }
    }

    // epilogue: D reg j -> row (lane>>4)*4+j, col lane&15
#pragma unroll
    for (int m = 0; m < 4; ++m) {
        int grow0 = bm + wr * 64 + m * 16 + l16 * 4;
#pragma unroll
        for (int n = 0; n < 4; ++n) {
            int gcol = bn + wc * 64 + n * 16 + l15;
#pragma unroll
            for (int j = 0; j < 4; ++j)
                C[(size_t)(grow0 + j) * N + gcol] = f2bf(acc[m][n][j]);
        }
    }
}

// ---------------- attention score dots: s[n,h] = sum_c h[n,h,c]*a[h,c] ----------------
template <int C>
__global__ void attn_scores_k(const ushort* __restrict__ h,
                              const float* __restrict__ asrc,
                              const float* __restrict__ adst,
                              float* __restrict__ ssrc, float* __restrict__ sdst) {
    constexpr int NT = C;        // threads; each handles 4 channels
    constexpr int G  = C / 4;    // threads per head
    int n = blockIdx.x, t = threadIdx.x;
    ushort4 hu = *reinterpret_cast<const ushort4*>(h + (size_t)n * 4 * C + 4 * t);
    float4 hv = make_float4(bf2f(hu.x), bf2f(hu.y), bf2f(hu.z), bf2f(hu.w));
    float4 av = *reinterpret_cast<const float4*>(asrc + 4 * t);
    float4 dv = *reinterpret_cast<const float4*>(adst + 4 * t);
    float ps = hv.x * av.x + hv.y * av.y + hv.z * av.z + hv.w * av.w;
    float pd = hv.x * dv.x + hv.y * dv.y + hv.z * dv.z + hv.w * dv.w;
    __shared__ float rs[NT], rd[NT];
    rs[t] = ps; rd[t] = pd;
    __syncthreads();
    for (int s_ = G / 2; s_ > 0; s_ >>= 1) {
        if ((t & (G - 1)) < s_) { rs[t] += rs[t + s_]; rd[t] += rd[t + s_]; }
        __syncthreads();
    }
    if ((t & (G - 1)) == 0) {
        int hh = t / G;
        ssrc[n * 4 + hh] = rs[t];
        sdst[n * 4 + hh] = rd[t];
    }
}

// ---------------- GAT softmax + aggregate (one block per dst node) ----------------
template <int C>
__global__ void aggregate_k(const ushort* __restrict__ hmat,
                            const float* __restrict__ ssrc,
                            const float* __restrict__ sdst,
                            const int* __restrict__ off,
                            const int* __restrict__ csr,
                            const float* __restrict__ bias,
                            ushort* __restrict__ out) {
    constexpr int HC = 4 * C, NT = HC / 8;   // each thread: 8 consecutive channels
    int n = blockIdx.x, t = threadIdx.x;
    int hh = (8 * t) / C;
    int beg = off[n], end = off[n + 1];
    __shared__ float4 red[NT];
    float4 sd = *reinterpret_cast<const float4*>(sdst + n * 4);

    // pass 1: per-head max of leaky_relu(ssrc[src]+sdst[n])
    float4 m4 = make_float4(-3e38f, -3e38f, -3e38f, -3e38f);
    for (int k = beg + t; k < end; k += NT) {
        int s = csr[k];
        float4 ss = *reinterpret_cast<const float4*>(ssrc + s * 4);
        m4 = f4max(m4, f4lrelu(f4add(ss, sd)));
    }
    red[t] = m4;
    __syncthreads();
    for (int s_ = NT / 2; s_ > 0; s_ >>= 1) {
        if (t < s_) red[t] = f4max(red[t], red[t + s_]);
        __syncthreads();
    }
    m4 = red[0];
    __syncthreads();

    // pass 2: denom
    float4 d4 = make_float4(0.f, 0.f, 0.f, 0.f);
    for (int k = beg + t; k < end; k += NT) {
        int s = csr[k];
        float4 ss = *reinterpret_cast<const float4*>(ssrc + s * 4);
        float4 e = f4lrelu(f4add(ss, sd));
        d4.x += __expf(e.x - m4.x);
        d4.y += __expf(e.y - m4.y);
        d4.z += __expf(e.z - m4.z);
        d4.w += __expf(e.w - m4.w);
    }
    red[t] = d4;
    __syncthreads();
    for (int s_ = NT / 2; s_ > 0; s_ >>= 1) {
        if (t < s_) red[t] = f4add(red[t], red[t + s_]);
        __syncthreads();
    }
    d4 = red[0];

    float mh  = f4comp(m4, hh);
    float rdh = 1.0f / (f4comp(d4, hh) + 1e-16f);
    float sdh = f4comp(sd, hh);

    // pass 3: weighted aggregation over in-edges (16B bf16 gathers)
    float acc[8] = {};
    for (int k = beg; k < end; ++k) {
        int s = csr[k];
        float ev = ssrc[s * 4 + hh] + sdh;
        ev = ev > 0.f ? ev : 0.2f * ev;
        float al = __expf(ev - mh) * rdh;
        uint4 hv = *reinterpret_cast<const uint4*>(hmat + (size_t)s * HC + 8 * t);
        acc[0] = fmaf(al, bf2f((ushort)(hv.x & 0xffff)), acc[0]);
        acc[1] = fmaf(al, bf2f((ushort)(hv.x >> 16)),    acc[1]);
        acc[2] = fmaf(al, bf2f((ushort)(hv.y & 0xffff)), acc[2]);
        acc[3] = fmaf(al, bf2f((ushort)(hv.y >> 16)),    acc[3]);
        acc[4] = fmaf(al, bf2f((ushort)(hv.z & 0xffff)), acc[4]);
        acc[5] = fmaf(al, bf2f((ushort)(hv.z >> 16)),    acc[5]);
        acc[6] = fmaf(al, bf2f((ushort)(hv.w & 0xffff)), acc[6]);
        acc[7] = fmaf(al, bf2f((ushort)(hv.w >> 16)),    acc[7]);
    }
    float4 b0 = *reinterpret_cast<const float4*>(bias + 8 * t);
    float4 b1 = *reinterpret_cast<const float4*>(bias + 8 * t + 4);
    uint4 o;
    o.x = (uint)f2bf(acc[0] + b0.x) | ((uint)f2bf(acc[1] + b0.y) << 16);
    o.y = (uint)f2bf(acc[2] + b0.z) | ((uint)f2bf(acc[3] + b0.w) << 16);
    o.z = (uint)f2bf(acc[4] + b1.x) | ((uint)f2bf(acc[5] + b1.y) << 16);
    o.w = (uint)f2bf(acc[6] + b1.z) | ((uint)f2bf(acc[7] + b1.w) << 16);
    *reinterpret_cast<uint4*>(out + (size_t)n * HC + 8 * t) = o;
}

// ---------------- relu + mean pool of one layer's block into pooled[:, coloff:] ----------------
__global__ void pool_k(const ushort* __restrict__ c, int HC,
                       float* __restrict__ pooled, int coloff, int per) {
    int g = blockIdx.x, t = threadIdx.x;   // HC/2 threads, 2 cols each
    const uint* base = reinterpret_cast<const uint*>(c + (size_t)g * per * HC) + t;
    float a0 = 0.f, a1 = 0.f;
    for (int r = 0; r < per; ++r) {
        uint v = base[(size_t)r * (HC / 2)];
        a0 += fmaxf(bf2f((ushort)(v & 0xffff)), 0.f);
        a1 += fmaxf(bf2f((ushort)(v >> 16)), 0.f);
    }
    float inv = 1.f / (float)per;
    *reinterpret_cast<float2*>(pooled + (size_t)g * 3072 + coloff + 2 * t) =
        make_float2(a0 * inv, a1 * inv);
}

// ---------------- dense1 stage A: split-K partials ----------------
// grid (1536/256, 3072/128, B/32); part[kt][g][j] = sum_{k in tile} pooled[g][k]*W[k][j]
__global__ __launch_bounds__(256) void dense1_part_k(
    const float* __restrict__ pooled, const float* __restrict__ W,
    float* __restrict__ part)
{
    const int t  = threadIdx.x;
    const int j  = blockIdx.x * 256 + t;     // output col
    const int k0 = blockIdx.y * 128;         // K tile
    const int g0 = blockIdx.z * 32;          // graph tile
    __shared__ float4 xs[32][32];            // [g][k/4] = 16 KB
#pragma unroll
    for (int u = 0; u < 4; ++u) {
        int id = t + u * 256;                // 0..1023
        int g  = id >> 5;
        int kq = id & 31;
        xs[g][kq] = *reinterpret_cast<const float4*>(
            pooled + (size_t)(g0 + g) * 3072 + k0 + kq * 4);
    }
    __syncthreads();
    float acc[32] = {};
    for (int kq = 0; kq < 32; ++kq) {
        float w0 = W[(size_t)(k0 + kq * 4 + 0) * 1536 + j];
        float w1 = W[(size_t)(k0 + kq * 4 + 1) * 1536 + j];
        float w2 = W[(size_t)(k0 + kq * 4 + 2) * 1536 + j];
        float w3 = W[(size_t)(k0 + kq * 4 + 3) * 1536 + j];
#pragma unroll
        for (int g = 0; g < 32; ++g) {
            float4 xv = xs[g][kq];
            acc[g] = fmaf(xv.x, w0, fmaf(xv.y, w1, fmaf(xv.z, w2, fmaf(xv.w, w3, acc[g]))));
        }
    }
    float* dst = part + ((size_t)blockIdx.y * gridDim.z * 32 + g0) * 1536 + j;
#pragma unroll
    for (int g = 0; g < 32; ++g)
        dst[(size_t)g * 1536] = acc[g];
}

// ---------------- dense1 stage B: reduce partials + bias + relu ----------------
__global__ void dense1_reduce_k(const float* __restrict__ part,
                                const float* __restrict__ bias,
                                float* __restrict__ h1, int total, int nkt) {
    int i = blockIdx.x * blockDim.x + threadIdx.x;   // over B*1536
    if (i >= total) return;
    int j = i % 1536;
    float s = bias[j];
    for (int kt = 0; kt < nkt; ++kt)
        s += part[(size_t)kt * total + i];
    h1[i] = s > 0.f ? s : 0.f;
}

// ---------------- LayerNorm + final linear ----------------
__global__ __launch_bounds__(256) void ln_head_k(const float* __restrict__ h1,
                                                 const float* __restrict__ gln,
                                                 const float* __restrict__ bln,
                                                 const float* __restrict__ W2,
                                                 const float* __restrict__ b2,
                                                 float* __restrict__ out) {
    int g = blockIdx.x, t = threadIdx.x;
    const float* row = h1 + (size_t)g * 1536;
    float v[6];
    float s = 0.f;
#pragma unroll
    for (int u = 0; u < 6; ++u) { v[u] = row[t + u * 256]; s += v[u]; }
    __shared__ float red[256];
    red[t] = s;
    __syncthreads();
    for (int d = 128; d > 0; d >>= 1) { if (t < d) red[t] += red[t + d]; __syncthreads(); }
    float mean = red[0] * (1.f / 1536.f);
    __syncthreads();
    float sq = 0.f;
#pragma unroll
    for (int u = 0; u < 6; ++u) { float z = v[u] - mean; sq += z * z; }
    red[t] = sq;
    __syncthreads();
    for (int d = 128; d > 0; d >>= 1) { if (t < d) red[t] += red[t + d]; __syncthreads(); }
    float var = red[0] * (1.f / 1536.f);
    __syncthreads();
    float rstd = rsqrtf(var + 1e-5f);
    float p = 0.f;
#pragma unroll
    for (int u = 0; u < 6; ++u) {
        int j = t + u * 256;
        float xn = (v[u] - mean) * rstd * gln[j] + bln[j];
        p = fmaf(xn, W2[j], p);
    }
    red[t] = p;
    __syncthreads();
    for (int d = 128; d > 0; d >>= 1) { if (t < d) red[t] += red[t + d]; __syncthreads(); }
    if (t == 0) out[g] = red[0] + b2[0] + 0.5f;
}

// ---------------- launch ----------------
extern "C" void kernel_launch(void* const* d_in, const int* in_sizes, int n_in,
                              void* d_out, int out_size, void* d_ws, size_t ws_size,
                              hipStream_t stream) {
    const float* x    = (const float*)d_in[0];
    const int*   ei   = (const int*)d_in[1];
    const float* Wg[4]  = {(const float*)d_in[3],  (const float*)d_in[7],
                           (const float*)d_in[11], (const float*)d_in[15]};
    const float* Asr[4] = {(const float*)d_in[4],  (const float*)d_in[8],
                           (const float*)d_in[12], (const float*)d_in[16]};
    const float* Ads[4] = {(const float*)d_in[5],  (const float*)d_in[9],
                           (const float*)d_in[13], (const float*)d_in[17]};
    const float* Bg[4]  = {(const float*)d_in[6],  (const float*)d_in[10],
                           (const float*)d_in[14], (const float*)d_in[18]};
    const float* Wd1 = (const float*)d_in[19];
    const float* bd1 = (const float*)d_in[20];
    const float* gln = (const float*)d_in[21];
    const float* bln = (const float*)d_in[22];
    const float* Wd2 = (const float*)d_in[23];
    const float* bd2 = (const float*)d_in[24];

    const int Nn = in_sizes[0] / 768;   // 40000
    const int E  = in_sizes[1] / 2;     // 480000
    const int Bb = Nn / 250;            // 160
    const int Np = ((Nn + 127) / 128) * 128;   // 40064, padded for MFMA tiles

    const int Kd[4]   = {768, 512, 512, 1024};
    const int Cd[4]   = {128, 128, 256, 256};
    const int coff[4] = {0, 512, 1024, 2048};

    // workspace carve (256B aligned) — total ~167 MB
    char* p = (char*)d_ws;
    auto alloc = [&](size_t bytes) -> void* {
        void* r = (void*)p;
        p += (bytes + 255) & ~(size_t)255;
        return r;
    };
    ushort* hbuf  = (ushort*)alloc((size_t)Np * 1024 * 2);   // h (bf16), padded rows
    ushort* cbuf  = (ushort*)alloc((size_t)Np * 1024 * 2);   // layer output (bf16)
    ushort* wt[4];
    for (int l = 0; l < 4; ++l)
        wt[l] = (ushort*)alloc((size_t)(4 * Cd[l]) * Kd[l] * 2);  // Wt[N][K] bf16
    float* ssrc   = (float*)alloc((size_t)Nn * 4 * 4);
    float* sdst   = (float*)alloc((size_t)Nn * 4 * 4);
    float* pooled = (float*)alloc((size_t)Bb * 3072 * 4);
    float* h1     = (float*)alloc((size_t)Bb * 1536 * 4);
    int* deg    = (int*)alloc((size_t)Nn * 4);
    int* cursor = (int*)alloc((size_t)Nn * 4);
    int* incl   = (int*)alloc((size_t)Nn * 4);
    int* bsum   = (int*)alloc(256 * 4);
    int* offs   = (int*)alloc((size_t)(Nn + 1) * 4);
    int* csr    = (int*)alloc((size_t)(E + Nn) * 4);

    size_t need = (size_t)(p - (char*)d_ws);
    if (need > ws_size) {
        fail_k<<<(out_size + 255) / 256, 256, 0, stream>>>((float*)d_out, out_size);
        return;
    }

    // weight transpose+convert (independent of CSR chain)
    for (int l = 0; l < 4; ++l) {
        int N = 4 * Cd[l], K = Kd[l];
        wconv_k<<<dim3(K / 32, N / 32), dim3(32, 8), 0, stream>>>(Wg[l], wt[l], K, N);
    }

    const int* esrc = ei;
    const int* edst = ei + E;
    const int nb = (Nn + 255) / 256;    // 157
    init_deg_k<<<nb, 256, 0, stream>>>(deg, cursor, Nn);
    count_deg_k<<<(E + 255) / 256, 256, 0, stream>>>(edst, deg, E);
    scan_part_k<<<nb, 256, 0, stream>>>(deg, incl, bsum, Nn);
    scan_block_k<<<1, 256, 0, stream>>>(bsum, nb);
    scan_final_k<<<nb, 256, 0, stream>>>(deg, incl, bsum, offs, Nn, E + Nn);
    fill_csr_k<<<(E + Nn + 255) / 256, 256, 0, stream>>>(esrc, edst, E, Nn, offs, cursor, csr);

    for (int l = 0; l < 4; ++l) {
        const int HC = 4 * Cd[l];
        dim3 gg(Np / 128, HC / 128);
        if (l == 0)
            gemm_mfma_k<1><<<gg, 256, 0, stream>>>(x, wt[0], hbuf, Nn, HC, Kd[0]);
        else
            gemm_mfma_k<0><<<gg, 256, 0, stream>>>(cbuf, wt[l], hbuf, Nn, HC, Kd[l]);
        // aggregate overwrites cbuf in place: c_{l-1} is dead after the GEMM above.
        if (Cd[l] == 128) {
            attn_scores_k<128><<<Nn, 128, 0, stream>>>(hbuf, Asr[l], Ads[l], ssrc, sdst);
            aggregate_k<128><<<Nn, 64, 0, stream>>>(hbuf, ssrc, sdst, offs, csr, Bg[l], cbuf);
            pool_k<<<Bb, 256, 0, stream>>>(cbuf, 512, pooled, coff[l], 250);
        } else {
            attn_scores_k<256><<<Nn, 256, 0, stream>>>(hbuf, Asr[l], Ads[l], ssrc, sdst);
            aggregate_k<256><<<Nn, 128, 0, stream>>>(hbuf, ssrc, sdst, offs, csr, Bg[l], cbuf);
            pool_k<<<Bb, 512, 0, stream>>>(cbuf, 1024, pooled, coff[l], 250);
        }
    }

    // dense1 split-K: partials into hbuf (dead scratch by now), then reduce
    float* part = (float*)hbuf;   // 24 * Bb * 1536 * 4 B = 23.6 MB << 80 MB
    dense1_part_k<<<dim3(6, 24, Bb / 32), 256, 0, stream>>>(pooled, Wd1, part);
    int total = Bb * 1536;
    dense1_reduce_k<<<(total + 255) / 256, 256, 0, stream>>>(part, bd1, h1, total, 24);

    ln_head_k<<<Bb, 256, 0, stream>>>(h1, gln, bln, Wd2, bd2, (float*)d_out);
}

// Round 12
// 1607.358 us; speedup vs baseline: 2.3961x; 1.0155x over previous
//
#include <hip/hip_runtime.h>
#include <hip/hip_bf16.h>
#include <math.h>

typedef unsigned int uint;
typedef unsigned short ushort;
typedef __attribute__((ext_vector_type(8))) short bf16x8;
typedef __attribute__((ext_vector_type(4))) float f32x4;

// ---------------- bf16 helpers (bit-level, RNE) ----------------
__device__ __forceinline__ float bf2f(ushort u) {
    union { uint u; float f; } v; v.u = ((uint)u) << 16; return v.f;
}
__device__ __forceinline__ ushort f2bf(float f) {
    union { float f; uint u; } v; v.f = f;
    uint r = v.u + 0x7fff + ((v.u >> 16) & 1);
    return (ushort)(r >> 16);
}

__device__ __forceinline__ void gl_lds16(const void* g, void* l) {
    __builtin_amdgcn_global_load_lds(
        (const __attribute__((address_space(1))) void*)g,
        (__attribute__((address_space(3))) void*)l, 16, 0, 0);
}

// ---------------- sentinel for insufficient workspace ----------------
__global__ void fail_k(float* out, int n) {
    int i = blockIdx.x * blockDim.x + threadIdx.x;
    if (i < n) out[i] = -12345.0f;
}

// ---------------- CSR build ----------------
__global__ void init_deg_k(int* __restrict__ deg, int* __restrict__ cursor, int Nn) {
    int i = blockIdx.x * blockDim.x + threadIdx.x;
    if (i < Nn) { deg[i] = 1; cursor[i] = 0; }   // 1 = self-loop
}

__global__ void count_deg_k(const int* __restrict__ edst, int* __restrict__ deg, int E) {
    int i = blockIdx.x * blockDim.x + threadIdx.x;
    if (i < E) atomicAdd(&deg[edst[i]], 1);
}

__global__ void scan_part_k(const int* __restrict__ deg, int* __restrict__ incl,
                            int* __restrict__ bsum, int Nn) {
    __shared__ int sh[256];
    int t = threadIdx.x;
    int i = blockIdx.x * 256 + t;
    int v = (i < Nn) ? deg[i] : 0;
    sh[t] = v;
    __syncthreads();
    for (int d = 1; d < 256; d <<= 1) {
        int add = (t >= d) ? sh[t - d] : 0;
        __syncthreads();
        sh[t] += add;
        __syncthreads();
    }
    if (i < Nn) incl[i] = sh[t];
    if (t == 255) bsum[blockIdx.x] = sh[255];
}

__global__ void scan_block_k(int* __restrict__ bsum, int nb) {
    __shared__ int sh[256];
    int t = threadIdx.x;
    sh[t] = (t < nb) ? bsum[t] : 0;
    __syncthreads();
    for (int d = 1; d < 256; d <<= 1) {
        int add = (t >= d) ? sh[t - d] : 0;
        __syncthreads();
        sh[t] += add;
        __syncthreads();
    }
    bsum[t] = sh[t];   // inclusive scan of block sums
}

__global__ void scan_final_k(const int* __restrict__ deg, const int* __restrict__ incl,
                             const int* __restrict__ bsum, int* __restrict__ off,
                             int Nn, int total) {
    int i = blockIdx.x * blockDim.x + threadIdx.x;
    if (i < Nn) {
        int b = i >> 8;
        int base = (b > 0) ? bsum[b - 1] : 0;
        off[i] = base + incl[i] - deg[i];   // exclusive
    }
    if (i == 0) off[Nn] = total;
}

__global__ void fill_csr_k(const int* __restrict__ esrc, const int* __restrict__ edst,
                           int E, int Nn, const int* __restrict__ off,
                           int* __restrict__ cursor, int* __restrict__ csr) {
    int i = blockIdx.x * blockDim.x + threadIdx.x;
    if (i < E) {
        int d = edst[i];
        int p = atomicAdd(&cursor[d], 1);
        csr[off[d] + p] = esrc[i];
    } else if (i < E + Nn) {
        int nd = i - E;
        int p = atomicAdd(&cursor[nd], 1);
        csr[off[nd] + p] = nd;              // self-loop
    }
}

// ---------------- W transpose+convert: Wt[n][k] = bf16(W[k][n]) ----------------
__global__ __launch_bounds__(256) void wconv_k(const float* __restrict__ W,
                                               ushort* __restrict__ Wt, int K, int N) {
    __shared__ float tile[32][33];
    int tx = threadIdx.x, ty = threadIdx.y;      // 32 x 8
    int k0 = blockIdx.x * 32, n0 = blockIdx.y * 32;
#pragma unroll
    for (int i = 0; i < 32; i += 8)
        tile[ty + i][tx] = W[(size_t)(k0 + ty + i) * N + n0 + tx];
    __syncthreads();
#pragma unroll
    for (int i = 0; i < 32; i += 8)
        Wt[(size_t)(n0 + ty + i) * K + k0 + tx] = f2bf(tile[tx][ty + i]);
}

// ---------------- MFMA GEMM: C_bf16[Mp,N] = A[Mp,K] @ Wt^T ----------------
// 128x128 tile, BK=64, 256 threads = 4 waves (2x2), 4x4 16x16 frags/wave.
// Grid: x = bn (fast-varying -> consecutive blocks share A-panel), y = bm.
template <int AF32>
__global__ __launch_bounds__(256) void gemm_mfma_k(
    const void* __restrict__ Av, const ushort* __restrict__ Bt,
    ushort* __restrict__ C, int M, int N, int K)
{
    constexpr int BM = 128, BN = 128, BK = 64;
    __shared__ __align__(16) ushort lds[(BM + BN) * BK];   // 32 KB: A then B
    ushort* Al = lds;
    ushort* Bl = lds + BM * BK;          // +8192 ushorts

    const int t = threadIdx.x;
    const int lane = t & 63;
    const int wave = t >> 6;
    const int wr = wave >> 1, wc = wave & 1;
    const int bm = blockIdx.y * BM, bn = blockIdx.x * BN;
    const int l15 = lane & 15, l16 = lane >> 4;

    f32x4 acc[4][4] = {};

    // B staging: 4 fragment-blocks per wave
    const ushort* gB[4];
    ushort* lB[4];
#pragma unroll
    for (int i = 0; i < 4; ++i) {
        int fb = wave * 4 + i, nb = fb >> 1, kb = fb & 1;
        gB[i] = Bt + (size_t)(bn + nb * 16 + l15) * K + kb * 32 + l16 * 8;
        lB[i] = Bl + fb * 512;
    }
    const ushort* gA[4] = {};
    ushort* lA[4] = {};
    const float* Af = (const float*)Av;
    int arow[4] = {}, akk[4] = {};
    if constexpr (AF32) {
#pragma unroll
        for (int i = 0; i < 4; ++i) {
            int c = t + 256 * i, fa = c >> 6, l = c & 63;
            int row = bm + (fa >> 1) * 16 + (l & 15);
            if (row >= M) row = M - 1;           // clamp: duplicate row, never stored
            arow[i] = row;
            akk[i] = (fa & 1) * 32 + (l >> 4) * 8;
        }
    } else {
        const ushort* Ab = (const ushort*)Av;
#pragma unroll
        for (int i = 0; i < 4; ++i) {
            int fa = wave * 4 + i, mb = fa >> 1, kb = fa & 1;
            gA[i] = Ab + (size_t)(bm + mb * 16 + l15) * K + kb * 32 + l16 * 8;
            lA[i] = Al + fa * 512;
        }
    }

    for (int k0 = 0; k0 < K; k0 += BK) {
        __syncthreads();                          // LDS free (prev compute done)
        if constexpr (AF32) {
#pragma unroll
            for (int i = 0; i < 4; ++i) {
                int c = t + 256 * i;
                const float* g = Af + (size_t)arow[i] * K + k0 + akk[i];
                float4 v0 = *(const float4*)g;
                float4 v1 = *(const float4*)(g + 4);
                uint4 o;
                o.x = (uint)f2bf(v0.x) | ((uint)f2bf(v0.y) << 16);
                o.y = (uint)f2bf(v0.z) | ((uint)f2bf(v0.w) << 16);
                o.z = (uint)f2bf(v1.x) | ((uint)f2bf(v1.y) << 16);
                o.w = (uint)f2bf(v1.z) | ((uint)f2bf(v1.w) << 16);
                *reinterpret_cast<uint4*>((char*)Al + (size_t)c * 16) = o;
            }
        } else {
#pragma unroll
            for (int i = 0; i < 4; ++i) { gl_lds16(gA[i], lA[i]); gA[i] += BK; }
        }
#pragma unroll
        for (int i = 0; i < 4; ++i) { gl_lds16(gB[i], lB[i]); gB[i] += BK; }
        __syncthreads();                          // stage complete (vmcnt drain)

#pragma unroll
        for (int kb = 0; kb < 2; ++kb) {
            bf16x8 a[4], b[4];
#pragma unroll
            for (int m = 0; m < 4; ++m)
                a[m] = *reinterpret_cast<const bf16x8*>(
                    Al + (((wr * 4 + m) * 2 + kb) * 64 + lane) * 8);
#pragma unroll
            for (int n = 0; n < 4; ++n)
                b[n] = *reinterpret_cast<const bf16x8*>(
                    Bl + (((wc * 4 + n) * 2 + kb) * 64 + lane) * 8);
#pragma unroll
            for (int m = 0; m < 4; ++m)
#pragma unroll
                for (int n = 0; n < 4; ++n)
                    acc[m][n] = __builtin_amdgcn_mfma_f32_16x16x32_bf16(
                        a[m], b[n], acc[m][n], 0, 0, 0);
        }
    }

    // epilogue: D reg j -> row (lane>>4)*4+j, col lane&15
#pragma unroll
    for (int m = 0; m < 4; ++m) {
        int grow0 = bm + wr * 64 + m * 16 + l16 * 4;
#pragma unroll
        for (int n = 0; n < 4; ++n) {
            int gcol = bn + wc * 64 + n * 16 + l15;
#pragma unroll
            for (int j = 0; j < 4; ++j)
                C[(size_t)(grow0 + j) * N + gcol] = f2bf(acc[m][n][j]);
        }
    }
}

// ---------------- attention score dots: s[n,h] = sum_c h[n,h,c]*a[h,c] ----------------
template <int C>
__global__ void attn_scores_k(const ushort* __restrict__ h,
                              const float* __restrict__ asrc,
                              const float* __restrict__ adst,
                              float* __restrict__ ssrc, float* __restrict__ sdst) {
    constexpr int NT = C;        // threads; each handles 4 channels
    constexpr int G  = C / 4;    // threads per head
    int n = blockIdx.x, t = threadIdx.x;
    ushort4 hu = *reinterpret_cast<const ushort4*>(h + (size_t)n * 4 * C + 4 * t);
    float4 hv = make_float4(bf2f(hu.x), bf2f(hu.y), bf2f(hu.z), bf2f(hu.w));
    float4 av = *reinterpret_cast<const float4*>(asrc + 4 * t);
    float4 dv = *reinterpret_cast<const float4*>(adst + 4 * t);
    float ps = hv.x * av.x + hv.y * av.y + hv.z * av.z + hv.w * av.w;
    float pd = hv.x * dv.x + hv.y * dv.y + hv.z * dv.z + hv.w * dv.w;
    __shared__ float rs[NT], rd[NT];
    rs[t] = ps; rd[t] = pd;
    __syncthreads();
    for (int s_ = G / 2; s_ > 0; s_ >>= 1) {
        if ((t & (G - 1)) < s_) { rs[t] += rs[t + s_]; rd[t] += rd[t + s_]; }
        __syncthreads();
    }
    if ((t & (G - 1)) == 0) {
        int hh = t / G;
        ssrc[n * 4 + hh] = rs[t];
        sdst[n * 4 + hh] = rd[t];
    }
}

// ---------------- GAT softmax + aggregate, single pass ----------------
// softmax is shift-invariant: out = (sum_e w_e * h_e) / (sum_e w_e), w = exp(lrelu(e)).
// |e| is O(10) for this model; clamp at 80 for absolute fp32-overflow safety.
// No LDS, no barriers; each thread owns 8 consecutive channels.
template <int C>
__global__ void aggregate_k(const ushort* __restrict__ hmat,
                            const float* __restrict__ ssrc,
                            const float* __restrict__ sdst,
                            const int* __restrict__ off,
                            const int* __restrict__ csr,
                            const float* __restrict__ bias,
                            ushort* __restrict__ out) {
    constexpr int HC = 4 * C, NT = HC / 8;   // each thread: 8 consecutive channels
    int n = blockIdx.x, t = threadIdx.x;
    int hh = (8 * t) / C;
    int beg = off[n], end = off[n + 1];
    float sdh = sdst[n * 4 + hh];

    float acc[8] = {};
    float dsum = 0.f;
    for (int k = beg; k < end; ++k) {
        int s = csr[k];
        float ev = ssrc[s * 4 + hh] + sdh;
        ev = ev > 0.f ? ev : 0.2f * ev;
        float w = __expf(fminf(ev, 80.f));
        dsum += w;
        uint4 hv = *reinterpret_cast<const uint4*>(hmat + (size_t)s * HC + 8 * t);
        acc[0] = fmaf(w, bf2f((ushort)(hv.x & 0xffff)), acc[0]);
        acc[1] = fmaf(w, bf2f((ushort)(hv.x >> 16)),    acc[1]);
        acc[2] = fmaf(w, bf2f((ushort)(hv.y & 0xffff)), acc[2]);
        acc[3] = fmaf(w, bf2f((ushort)(hv.y >> 16)),    acc[3]);
        acc[4] = fmaf(w, bf2f((ushort)(hv.z & 0xffff)), acc[4]);
        acc[5] = fmaf(w, bf2f((ushort)(hv.z >> 16)),    acc[5]);
        acc[6] = fmaf(w, bf2f((ushort)(hv.w & 0xffff)), acc[6]);
        acc[7] = fmaf(w, bf2f((ushort)(hv.w >> 16)),    acc[7]);
    }
    float inv = 1.0f / (dsum + 1e-16f);
    float4 b0 = *reinterpret_cast<const float4*>(bias + 8 * t);
    float4 b1 = *reinterpret_cast<const float4*>(bias + 8 * t + 4);
    uint4 o;
    o.x = (uint)f2bf(fmaf(acc[0], inv, b0.x)) | ((uint)f2bf(fmaf(acc[1], inv, b0.y)) << 16);
    o.y = (uint)f2bf(fmaf(acc[2], inv, b0.z)) | ((uint)f2bf(fmaf(acc[3], inv, b0.w)) << 16);
    o.z = (uint)f2bf(fmaf(acc[4], inv, b1.x)) | ((uint)f2bf(fmaf(acc[5], inv, b1.y)) << 16);
    o.w = (uint)f2bf(fmaf(acc[6], inv, b1.z)) | ((uint)f2bf(fmaf(acc[7], inv, b1.w)) << 16);
    *reinterpret_cast<uint4*>(out + (size_t)n * HC + 8 * t) = o;
}

// ---------------- relu + mean pool of one layer's block into pooled[:, coloff:] ----------------
__global__ void pool_k(const ushort* __restrict__ c, int HC,
                       float* __restrict__ pooled, int coloff, int per) {
    int g = blockIdx.x, t = threadIdx.x;   // HC/2 threads, 2 cols each
    const uint* base = reinterpret_cast<const uint*>(c + (size_t)g * per * HC) + t;
    float a0 = 0.f, a1 = 0.f;
    for (int r = 0; r < per; ++r) {
        uint v = base[(size_t)r * (HC / 2)];
        a0 += fmaxf(bf2f((ushort)(v & 0xffff)), 0.f);
        a1 += fmaxf(bf2f((ushort)(v >> 16)), 0.f);
    }
    float inv = 1.f / (float)per;
    *reinterpret_cast<float2*>(pooled + (size_t)g * 3072 + coloff + 2 * t) =
        make_float2(a0 * inv, a1 * inv);
}

// ---------------- dense1 stage A: split-K partials ----------------
// grid (1536/256, 3072/128, B/32); part[kt][g][j] = sum_{k in tile} pooled[g][k]*W[k][j]
__global__ __launch_bounds__(256) void dense1_part_k(
    const float* __restrict__ pooled, const float* __restrict__ W,
    float* __restrict__ part)
{
    const int t  = threadIdx.x;
    const int j  = blockIdx.x * 256 + t;     // output col
    const int k0 = blockIdx.y * 128;         // K tile
    const int g0 = blockIdx.z * 32;          // graph tile
    __shared__ float4 xs[32][32];            // [g][k/4] = 16 KB
#pragma unroll
    for (int u = 0; u < 4; ++u) {
        int id = t + u * 256;                // 0..1023
        int g  = id >> 5;
        int kq = id & 31;
        xs[g][kq] = *reinterpret_cast<const float4*>(
            pooled + (size_t)(g0 + g) * 3072 + k0 + kq * 4);
    }
    __syncthreads();
    float acc[32] = {};
    for (int kq = 0; kq < 32; ++kq) {
        float w0 = W[(size_t)(k0 + kq * 4 + 0) * 1536 + j];
        float w1 = W[(size_t)(k0 + kq * 4 + 1) * 1536 + j];
        float w2 = W[(size_t)(k0 + kq * 4 + 2) * 1536 + j];
        float w3 = W[(size_t)(k0 + kq * 4 + 3) * 1536 + j];
#pragma unroll
        for (int g = 0; g < 32; ++g) {
            float4 xv = xs[g][kq];
            acc[g] = fmaf(xv.x, w0, fmaf(xv.y, w1, fmaf(xv.z, w2, fmaf(xv.w, w3, acc[g]))));
        }
    }
    float* dst = part + ((size_t)blockIdx.y * gridDim.z * 32 + g0) * 1536 + j;
#pragma unroll
    for (int g = 0; g < 32; ++g)
        dst[(size_t)g * 1536] = acc[g];
}

// ---------------- dense1 stage B: reduce partials + bias + relu ----------------
__global__ void dense1_reduce_k(const float* __restrict__ part,
                                const float* __restrict__ bias,
                                float* __restrict__ h1, int total, int nkt) {
    int i = blockIdx.x * blockDim.x + threadIdx.x;   // over B*1536
    if (i >= total) return;
    int j = i % 1536;
    float s = bias[j];
    for (int kt = 0; kt < nkt; ++kt)
        s += part[(size_t)kt * total + i];
    h1[i] = s > 0.f ? s : 0.f;
}

// ---------------- LayerNorm + final linear ----------------
__global__ __launch_bounds__(256) void ln_head_k(const float* __restrict__ h1,
                                                 const float* __restrict__ gln,
                                                 const float* __restrict__ bln,
                                                 const float* __restrict__ W2,
                                                 const float* __restrict__ b2,
                                                 float* __restrict__ out) {
    int g = blockIdx.x, t = threadIdx.x;
    const float* row = h1 + (size_t)g * 1536;
    float v[6];
    float s = 0.f;
#pragma unroll
    for (int u = 0; u < 6; ++u) { v[u] = row[t + u * 256]; s += v[u]; }
    __shared__ float red[256];
    red[t] = s;
    __syncthreads();
    for (int d = 128; d > 0; d >>= 1) { if (t < d) red[t] += red[t + d]; __syncthreads(); }
    float mean = red[0] * (1.f / 1536.f);
    __syncthreads();
    float sq = 0.f;
#pragma unroll
    for (int u = 0; u < 6; ++u) { float z = v[u] - mean; sq += z * z; }
    red[t] = sq;
    __syncthreads();
    for (int d = 128; d > 0; d >>= 1) { if (t < d) red[t] += red[t + d]; __syncthreads(); }
    float var = red[0] * (1.f / 1536.f);
    __syncthreads();
    float rstd = rsqrtf(var + 1e-5f);
    float p = 0.f;
#pragma unroll
    for (int u = 0; u < 6; ++u) {
        int j = t + u * 256;
        float xn = (v[u] - mean) * rstd * gln[j] + bln[j];
        p = fmaf(xn, W2[j], p);
    }
    red[t] = p;
    __syncthreads();
    for (int d = 128; d > 0; d >>= 1) { if (t < d) red[t] += red[t + d]; __syncthreads(); }
    if (t == 0) out[g] = red[0] + b2[0] + 0.5f;
}

// ---------------- launch ----------------
extern "C" void kernel_launch(void* const* d_in, const int* in_sizes, int n_in,
                              void* d_out, int out_size, void* d_ws, size_t ws_size,
                              hipStream_t stream) {
    const float* x    = (const float*)d_in[0];
    const int*   ei   = (const int*)d_in[1];
    const float* Wg[4]  = {(const float*)d_in[3],  (const float*)d_in[7],
                           (const float*)d_in[11], (const float*)d_in[15]};
    const float* Asr[4] = {(const float*)d_in[4],  (const float*)d_in[8],
                           (const float*)d_in[12], (const float*)d_in[16]};
    const float* Ads[4] = {(const float*)d_in[5],  (const float*)d_in[9],
                           (const float*)d_in[13], (const float*)d_in[17]};
    const float* Bg[4]  = {(const float*)d_in[6],  (const float*)d_in[10],
                           (const float*)d_in[14], (const float*)d_in[18]};
    const float* Wd1 = (const float*)d_in[19];
    const float* bd1 = (const float*)d_in[20];
    const float* gln = (const float*)d_in[21];
    const float* bln = (const float*)d_in[22];
    const float* Wd2 = (const float*)d_in[23];
    const float* bd2 = (const float*)d_in[24];

    const int Nn = in_sizes[0] / 768;   // 40000
    const int E  = in_sizes[1] / 2;     // 480000
    const int Bb = Nn / 250;            // 160
    const int Np = ((Nn + 127) / 128) * 128;   // 40064, padded for MFMA tiles

    const int Kd[4]   = {768, 512, 512, 1024};
    const int Cd[4]   = {128, 128, 256, 256};
    const int coff[4] = {0, 512, 1024, 2048};

    // workspace carve (256B aligned) — total ~167 MB
    char* p = (char*)d_ws;
    auto alloc = [&](size_t bytes) -> void* {
        void* r = (void*)p;
        p += (bytes + 255) & ~(size_t)255;
        return r;
    };
    ushort* hbuf  = (ushort*)alloc((size_t)Np * 1024 * 2);   // h (bf16), padded rows
    ushort* cbuf  = (ushort*)alloc((size_t)Np * 1024 * 2);   // layer output (bf16)
    ushort* wt[4];
    for (int l = 0; l < 4; ++l)
        wt[l] = (ushort*)alloc((size_t)(4 * Cd[l]) * Kd[l] * 2);  // Wt[N][K] bf16
    float* ssrc   = (float*)alloc((size_t)Nn * 4 * 4);
    float* sdst   = (float*)alloc((size_t)Nn * 4 * 4);
    float* pooled = (float*)alloc((size_t)Bb * 3072 * 4);
    float* h1     = (float*)alloc((size_t)Bb * 1536 * 4);
    int* deg    = (int*)alloc((size_t)Nn * 4);
    int* cursor = (int*)alloc((size_t)Nn * 4);
    int* incl   = (int*)alloc((size_t)Nn * 4);
    int* bsum   = (int*)alloc(256 * 4);
    int* offs   = (int*)alloc((size_t)(Nn + 1) * 4);
    int* csr    = (int*)alloc((size_t)(E + Nn) * 4);

    size_t need = (size_t)(p - (char*)d_ws);
    if (need > ws_size) {
        fail_k<<<(out_size + 255) / 256, 256, 0, stream>>>((float*)d_out, out_size);
        return;
    }

    // weight transpose+convert (independent of CSR chain)
    for (int l = 0; l < 4; ++l) {
        int N = 4 * Cd[l], K = Kd[l];
        wconv_k<<<dim3(K / 32, N / 32), dim3(32, 8), 0, stream>>>(Wg[l], wt[l], K, N);
    }

    const int* esrc = ei;
    const int* edst = ei + E;
    const int nb = (Nn + 255) / 256;    // 157
    init_deg_k<<<nb, 256, 0, stream>>>(deg, cursor, Nn);
    count_deg_k<<<(E + 255) / 256, 256, 0, stream>>>(edst, deg, E);
    scan_part_k<<<nb, 256, 0, stream>>>(deg, incl, bsum, Nn);
    scan_block_k<<<1, 256, 0, stream>>>(bsum, nb);
    scan_final_k<<<nb, 256, 0, stream>>>(deg, incl, bsum, offs, Nn, E + Nn);
    fill_csr_k<<<(E + Nn + 255) / 256, 256, 0, stream>>>(esrc, edst, E, Nn, offs, cursor, csr);

    for (int l = 0; l < 4; ++l) {
        const int HC = 4 * Cd[l];
        dim3 gg(HC / 128, Np / 128);   // x = bn (fast) -> consecutive blocks share A-panel
        if (l == 0)
            gemm_mfma_k<1><<<gg, 256, 0, stream>>>(x, wt[0], hbuf, Nn, HC, Kd[0]);
        else
            gemm_mfma_k<0><<<gg, 256, 0, stream>>>(cbuf, wt[l], hbuf, Nn, HC, Kd[l]);
        // aggregate overwrites cbuf in place: c_{l-1} is dead after the GEMM above.
        if (Cd[l] == 128) {
            attn_scores_k<128><<<Nn, 128, 0, stream>>>(hbuf, Asr[l], Ads[l], ssrc, sdst);
            aggregate_k<128><<<Nn, 64, 0, stream>>>(hbuf, ssrc, sdst, offs, csr, Bg[l], cbuf);
            pool_k<<<Bb, 256, 0, stream>>>(cbuf, 512, pooled, coff[l], 250);
        } else {
            attn_scores_k<256><<<Nn, 256, 0, stream>>>(hbuf, Asr[l], Ads[l], ssrc, sdst);
            aggregate_k<256><<<Nn, 128, 0, stream>>>(hbuf, ssrc, sdst, offs, csr, Bg[l], cbuf);
            pool_k<<<Bb, 512, 0, stream>>>(cbuf, 1024, pooled, coff[l], 250);
        }
    }

    // dense1 split-K: partials into hbuf (dead scratch by now), then reduce
    float* part = (float*)hbuf;   // 24 * Bb * 1536 * 4 B = 23.6 MB << 80 MB
    dense1_part_k<<<dim3(6, 24, Bb / 32), 256, 0, stream>>>(pooled, Wd1, part);
    int total = Bb * 1536;
    dense1_reduce_k<<<(total + 255) / 256, 256, 0, stream>>>(part, bd1, h1, total, 24);

    ln_head_k<<<Bb, 256, 0, stream>>>(h1, gln, bln, Wd2, bd2, (float*)d_out);
}